// Round 1
// baseline (472.693 us; speedup 1.0000x reference)
//
#include <hip/hip_runtime.h>
#include <math.h>

// Problem constants (match reference)
#define FIN   128
#define HC1   128   // H*C for layer 1
#define NCLS  16
#define NEG_SLOPE 0.2f

// ---------------------------------------------------------------------------
// CSR build kernels (dst -> incoming edge list), shared by both layers
// ---------------------------------------------------------------------------
__global__ void hist_kernel(const int* __restrict__ ei, int* __restrict__ cnt,
                            int E, int N) {
    int e = blockIdx.x * blockDim.x + threadIdx.x;
    int tot = E + N;
    if (e >= tot) return;
    int d = (e < E) ? ei[E + e] : (e - E);   // self-loop dst = node id
    atomicAdd(&cnt[d], 1);
}

__global__ __launch_bounds__(1024)
void scan_kernel(const int* __restrict__ cnt, int* __restrict__ offs,
                 int* __restrict__ cursor, int N) {
    __shared__ int lds[1024];
    int t = threadIdx.x;
    const int CH = (N + 1023) / 1024;
    int base = t * CH;
    int local = 0;
    for (int j = 0; j < CH; ++j) {
        int i = base + j;
        if (i < N) local += cnt[i];
    }
    lds[t] = local;
    __syncthreads();
    for (int off = 1; off < 1024; off <<= 1) {
        int v = (t >= off) ? lds[t - off] : 0;
        __syncthreads();
        lds[t] += v;
        __syncthreads();
    }
    int run = lds[t] - local;   // exclusive prefix
    for (int j = 0; j < CH; ++j) {
        int i = base + j;
        if (i < N) {
            offs[i] = run;
            cursor[i] = run;
            run += cnt[i];
        }
    }
    if (t == 1023) offs[N] = lds[1023];
}

__global__ void scatter_kernel(const int* __restrict__ ei, int* __restrict__ cursor,
                               int* __restrict__ csr_src, int E, int N) {
    int e = blockIdx.x * blockDim.x + threadIdx.x;
    int tot = E + N;
    if (e >= tot) return;
    int d, s;
    if (e < E) { d = ei[E + e]; s = ei[e]; }
    else       { d = e - E;     s = e - E; }
    int pos = atomicAdd(&cursor[d], 1);
    csr_src[pos] = s;
}

// ---------------------------------------------------------------------------
// Layer 1 GEMM: h1[N][128] = x @ W1  (no bias here; bias is post-aggregation)
// + fused alpha_src1/alpha_dst1 per (node, head) via wave reduction.
// Block: 128 threads (thread = output column), 16 nodes per block.
// ---------------------------------------------------------------------------
#define NPB1 16
__global__ __launch_bounds__(128)
void gemm1_alpha(const float* __restrict__ x, const float* __restrict__ W,
                 const float* __restrict__ a_src, const float* __restrict__ a_dst,
                 float* __restrict__ h1, float* __restrict__ as1, float* __restrict__ ad1,
                 int N) {
    __shared__ float xs[NPB1][FIN];
    int tid = threadIdx.x;          // output column 0..127 (head = tid>>6)
    int n0 = blockIdx.x * NPB1;
    for (int r = 0; r < NPB1; ++r) {
        int n = n0 + r;
        xs[r][tid] = (n < N) ? x[(long)n * FIN + tid] : 0.f;
    }
    __syncthreads();

    float acc[NPB1];
#pragma unroll
    for (int r = 0; r < NPB1; ++r) acc[r] = 0.f;

    for (int k = 0; k < FIN; k += 4) {
        float w0 = W[(k + 0) * HC1 + tid];
        float w1 = W[(k + 1) * HC1 + tid];
        float w2 = W[(k + 2) * HC1 + tid];
        float w3 = W[(k + 3) * HC1 + tid];
#pragma unroll
        for (int r = 0; r < NPB1; ++r) {
            float4 xv = *reinterpret_cast<const float4*>(&xs[r][k]);
            acc[r] = fmaf(xv.x, w0, acc[r]);
            acc[r] = fmaf(xv.y, w1, acc[r]);
            acc[r] = fmaf(xv.z, w2, acc[r]);
            acc[r] = fmaf(xv.w, w3, acc[r]);
        }
    }

    float av_s = a_src[tid];   // att_src1 flat [2*64] == column index
    float av_d = a_dst[tid];
    int head = tid >> 6;
#pragma unroll
    for (int r = 0; r < NPB1; ++r) {
        int n = n0 + r;
        if (n >= N) break;
        h1[(long)n * HC1 + tid] = acc[r];
        float s = acc[r] * av_s;
        float d = acc[r] * av_d;
        for (int off = 32; off >= 1; off >>= 1) {
            s += __shfl_down(s, off, 64);
            d += __shfl_down(d, off, 64);
        }
        if ((tid & 63) == 0) {
            as1[n * 2 + head] = s;
            ad1[n * 2 + head] = d;
        }
    }
}

// ---------------------------------------------------------------------------
// Layer 1 aggregation: per node, segment softmax over incoming edges + weighted
// sum of h1[src], + b1, ELU -> h2. Block = 128 threads (2 waves = 2 heads),
// one node per block.
// ---------------------------------------------------------------------------
__global__ __launch_bounds__(128)
void aggregate1(const int* __restrict__ offs, const int* __restrict__ csr,
                const float* __restrict__ h1, const float* __restrict__ as1,
                const float* __restrict__ ad1, const float* __restrict__ b1,
                float* __restrict__ h2, int N) {
    int n = blockIdx.x;
    if (n >= N) return;
    int tid = threadIdx.x;
    int head = tid >> 6;
    int s0 = offs[n], s1 = offs[n + 1];
    float adn = ad1[n * 2 + head];

    float m = -1e30f;
    for (int i = s0; i < s1; ++i) {
        int s = csr[i];
        float v = as1[s * 2 + head] + adn;
        v = (v >= 0.f) ? v : NEG_SLOPE * v;
        m = fmaxf(m, v);
    }
    float den = 0.f, acc = 0.f;
    for (int i = s0; i < s1; ++i) {
        int s = csr[i];
        float v = as1[s * 2 + head] + adn;
        v = (v >= 0.f) ? v : NEG_SLOPE * v;
        float p = __expf(v - m);
        den += p;
        acc = fmaf(h1[(long)s * HC1 + tid], p, acc);
    }
    float o = acc / (den + 1e-16f) + b1[tid];
    h2[(long)n * HC1 + tid] = (o > 0.f) ? o : expm1f(o);   // ELU
}

// ---------------------------------------------------------------------------
// Layer 2 GEMM: z[N][16] = h2 @ W2 (+ fused alpha2 over 16-lane groups)
// Block 256 = 16 nodes x 16 cols.
// ---------------------------------------------------------------------------
__global__ __launch_bounds__(256)
void gemm2_alpha(const float* __restrict__ h2, const float* __restrict__ W2,
                 const float* __restrict__ a_src, const float* __restrict__ a_dst,
                 float* __restrict__ z, float* __restrict__ as2, float* __restrict__ ad2,
                 int N) {
    __shared__ float hs[16][FIN + 4];
    __shared__ float ws[FIN * NCLS];
    int tid = threadIdx.x;
    int n0 = blockIdx.x * 16;
    for (int i = tid; i < FIN * NCLS; i += 256) ws[i] = W2[i];
    for (int i = tid; i < 16 * FIN; i += 256) {
        int r = i >> 7, c = i & 127;
        int n = n0 + r;
        hs[r][c] = (n < N) ? h2[(long)n * FIN + c] : 0.f;
    }
    __syncthreads();

    int r = tid >> 4, c = tid & 15;
    int n = n0 + r;
    float acc = 0.f;
#pragma unroll 4
    for (int k = 0; k < FIN; ++k)
        acc = fmaf(hs[r][k], ws[k * NCLS + c], acc);

    float sa = acc * a_src[c];
    float da = acc * a_dst[c];
    for (int off = 8; off >= 1; off >>= 1) {
        sa += __shfl_xor(sa, off, 16);
        da += __shfl_xor(da, off, 16);
    }
    if (n < N) {
        z[n * NCLS + c] = acc;
        if (c == 0) { as2[n] = sa; ad2[n] = da; }
    }
}

// ---------------------------------------------------------------------------
// Layer 2 aggregation + bias + log_softmax. 16 lanes per node, block 256.
// ---------------------------------------------------------------------------
__global__ __launch_bounds__(256)
void aggregate2(const int* __restrict__ offs, const int* __restrict__ csr,
                const float* __restrict__ z, const float* __restrict__ as2,
                const float* __restrict__ ad2, const float* __restrict__ b2,
                float* __restrict__ out, int N) {
    int tid = threadIdx.x;
    int n = blockIdx.x * 16 + (tid >> 4);
    int c = tid & 15;
    if (n >= N) return;
    int s0 = offs[n], s1 = offs[n + 1];
    float adn = ad2[n];

    float m = -1e30f;
    for (int i = s0; i < s1; ++i) {
        float v = as2[csr[i]] + adn;
        v = (v >= 0.f) ? v : NEG_SLOPE * v;
        m = fmaxf(m, v);
    }
    float den = 0.f, acc = 0.f;
    for (int i = s0; i < s1; ++i) {
        int s = csr[i];
        float v = as2[s] + adn;
        v = (v >= 0.f) ? v : NEG_SLOPE * v;
        float p = __expf(v - m);
        den += p;
        acc = fmaf(z[s * NCLS + c], p, acc);
    }
    float o = acc / (den + 1e-16f) + b2[c];

    // log_softmax over the 16 classes (16-lane group)
    float mx = o;
    for (int off = 8; off >= 1; off >>= 1) mx = fmaxf(mx, __shfl_xor(mx, off, 16));
    float ex = __expf(o - mx);
    float sum = ex;
    for (int off = 8; off >= 1; off >>= 1) sum += __shfl_xor(sum, off, 16);
    out[n * NCLS + c] = o - mx - __logf(sum);
}

// ---------------------------------------------------------------------------
extern "C" void kernel_launch(void* const* d_in, const int* in_sizes, int n_in,
                              void* d_out, int out_size, void* d_ws, size_t ws_size,
                              hipStream_t stream) {
    const float* x        = (const float*)d_in[0];
    const int*   ei       = (const int*)  d_in[1];
    // d_in[2] = edge_attr (unused by reference)
    const float* W1       = (const float*)d_in[3];
    const float* att_src1 = (const float*)d_in[4];
    const float* att_dst1 = (const float*)d_in[5];
    const float* b1       = (const float*)d_in[6];
    const float* W2       = (const float*)d_in[7];
    const float* att_src2 = (const float*)d_in[8];
    const float* att_dst2 = (const float*)d_in[9];
    const float* b2       = (const float*)d_in[10];
    float* out = (float*)d_out;

    const int N = in_sizes[0] / FIN;        // 50000
    const int E = in_sizes[1] / 2;          // 800000
    const int Etot = E + N;                 // self-loops appended

    // Workspace layout (bytes)
    char* ws = (char*)d_ws;
    size_t off = 0;
    auto alloc = [&](size_t bytes) { char* p = ws + off; off += (bytes + 255) & ~(size_t)255; return p; };
    int*   cnt    = (int*)  alloc((size_t)N * 4);
    int*   offs   = (int*)  alloc((size_t)(N + 1) * 4);
    int*   cursor = (int*)  alloc((size_t)N * 4);
    int*   csr    = (int*)  alloc((size_t)Etot * 4);
    float* h1     = (float*)alloc((size_t)N * HC1 * 4);
    float* h2     = (float*)alloc((size_t)N * HC1 * 4);
    float* z      = (float*)alloc((size_t)N * NCLS * 4);
    float* as1    = (float*)alloc((size_t)N * 2 * 4);
    float* ad1    = (float*)alloc((size_t)N * 2 * 4);
    float* as2    = (float*)alloc((size_t)N * 4);
    float* ad2    = (float*)alloc((size_t)N * 4);
    (void)ws_size;

    hipMemsetAsync(cnt, 0, (size_t)N * 4, stream);

    int tb = 256;
    int eb = (Etot + tb - 1) / tb;
    hist_kernel<<<eb, tb, 0, stream>>>(ei, cnt, E, N);
    scan_kernel<<<1, 1024, 0, stream>>>(cnt, offs, cursor, N);
    scatter_kernel<<<eb, tb, 0, stream>>>(ei, cursor, csr, E, N);

    gemm1_alpha<<<(N + NPB1 - 1) / NPB1, 128, 0, stream>>>(
        x, W1, att_src1, att_dst1, h1, as1, ad1, N);
    aggregate1<<<N, 128, 0, stream>>>(offs, csr, h1, as1, ad1, b1, h2, N);
    gemm2_alpha<<<(N + 15) / 16, 256, 0, stream>>>(
        h2, W2, att_src2, att_dst2, z, as2, ad2, N);
    aggregate2<<<(N + 15) / 16, 256, 0, stream>>>(offs, csr, z, as2, ad2, b2, out, N);
}

// Round 2
// 461.555 us; speedup vs baseline: 1.0241x; 1.0241x over previous
//
#include <hip/hip_runtime.h>
#include <math.h>

// Problem constants (match reference)
#define FIN   128
#define HC1   128   // H*C for layer 1
#define NCLS  16
#define NEG_SLOPE 0.2f

// ---------------------------------------------------------------------------
// CSR build kernels (dst -> incoming edge list), shared by both layers
// ---------------------------------------------------------------------------
__global__ void hist_kernel(const int* __restrict__ ei, int* __restrict__ cnt,
                            int E, int N) {
    int e = blockIdx.x * blockDim.x + threadIdx.x;
    int tot = E + N;
    if (e >= tot) return;
    int d = (e < E) ? ei[E + e] : (e - E);   // self-loop dst = node id
    atomicAdd(&cnt[d], 1);
}

__global__ __launch_bounds__(1024)
void scan_kernel(const int* __restrict__ cnt, int* __restrict__ offs,
                 int* __restrict__ cursor, int N) {
    __shared__ int lds[1024];
    int t = threadIdx.x;
    const int CH = (N + 1023) / 1024;
    int base = t * CH;
    int local = 0;
    for (int j = 0; j < CH; ++j) {
        int i = base + j;
        if (i < N) local += cnt[i];
    }
    lds[t] = local;
    __syncthreads();
    for (int off = 1; off < 1024; off <<= 1) {
        int v = (t >= off) ? lds[t - off] : 0;
        __syncthreads();
        lds[t] += v;
        __syncthreads();
    }
    int run = lds[t] - local;   // exclusive prefix
    for (int j = 0; j < CH; ++j) {
        int i = base + j;
        if (i < N) {
            offs[i] = run;
            cursor[i] = run;
            run += cnt[i];
        }
    }
    if (t == 1023) offs[N] = lds[1023];
}

__global__ void scatter_kernel(const int* __restrict__ ei, int* __restrict__ cursor,
                               int* __restrict__ csr_src, int E, int N) {
    int e = blockIdx.x * blockDim.x + threadIdx.x;
    int tot = E + N;
    if (e >= tot) return;
    int d, s;
    if (e < E) { d = ei[E + e]; s = ei[e]; }
    else       { d = e - E;     s = e - E; }
    int pos = atomicAdd(&cursor[d], 1);
    csr_src[pos] = s;
}

// ---------------------------------------------------------------------------
// Layer 1 GEMM: h1[N][128] = x @ W1 + fused alpha scalars (unchanged)
// ---------------------------------------------------------------------------
#define NPB1 16
__global__ __launch_bounds__(128)
void gemm1_alpha(const float* __restrict__ x, const float* __restrict__ W,
                 const float* __restrict__ a_src, const float* __restrict__ a_dst,
                 float* __restrict__ h1, float* __restrict__ as1, float* __restrict__ ad1,
                 int N) {
    __shared__ float xs[NPB1][FIN];
    int tid = threadIdx.x;          // output column 0..127 (head = tid>>6)
    int n0 = blockIdx.x * NPB1;
    for (int r = 0; r < NPB1; ++r) {
        int n = n0 + r;
        xs[r][tid] = (n < N) ? x[(long)n * FIN + tid] : 0.f;
    }
    __syncthreads();

    float acc[NPB1];
#pragma unroll
    for (int r = 0; r < NPB1; ++r) acc[r] = 0.f;

    for (int k = 0; k < FIN; k += 4) {
        float w0 = W[(k + 0) * HC1 + tid];
        float w1 = W[(k + 1) * HC1 + tid];
        float w2 = W[(k + 2) * HC1 + tid];
        float w3 = W[(k + 3) * HC1 + tid];
#pragma unroll
        for (int r = 0; r < NPB1; ++r) {
            float4 xv = *reinterpret_cast<const float4*>(&xs[r][k]);
            acc[r] = fmaf(xv.x, w0, acc[r]);
            acc[r] = fmaf(xv.y, w1, acc[r]);
            acc[r] = fmaf(xv.z, w2, acc[r]);
            acc[r] = fmaf(xv.w, w3, acc[r]);
        }
    }

    float av_s = a_src[tid];
    float av_d = a_dst[tid];
    int head = tid >> 6;
#pragma unroll
    for (int r = 0; r < NPB1; ++r) {
        int n = n0 + r;
        if (n >= N) break;
        h1[(long)n * HC1 + tid] = acc[r];
        float s = acc[r] * av_s;
        float d = acc[r] * av_d;
        for (int off = 32; off >= 1; off >>= 1) {
            s += __shfl_down(s, off, 64);
            d += __shfl_down(d, off, 64);
        }
        if ((tid & 63) == 0) {
            as1[n * 2 + head] = s;
            ad1[n * 2 + head] = d;
        }
    }
}

// ---------------------------------------------------------------------------
// Layer 1 aggregation v2: block(256) per node.
// Stage 1: 128 edge-slots x 2 heads parallel score max/sum (LDS tree).
// Stage 2: 8 edge-groups x 32 lanes x float4 row gather; LDS cross-group
// reduce; fused bias + ELU.
// ---------------------------------------------------------------------------
__global__ __launch_bounds__(256)
void aggregate1_v2(const int* __restrict__ offs, const int* __restrict__ csr,
                   const float* __restrict__ h1, const float* __restrict__ as1,
                   const float* __restrict__ ad1, const float* __restrict__ b1,
                   float* __restrict__ h2, int N) {
    __shared__ float red[256];
    __shared__ float m_s[2], rd_s[2];
    __shared__ float accs[8][HC1];

    int n = blockIdx.x;
    int tid = threadIdx.x;
    int s0 = offs[n], s1 = offs[n + 1];
    int deg = s1 - s0;
    int slot = tid >> 1, h = tid & 1;
    float adn0 = ad1[n * 2 + 0];
    float adn1 = ad1[n * 2 + 1];
    float adn = h ? adn1 : adn0;

    // stage 1a: max
    float lm = -1e30f;
    for (int i = slot; i < deg; i += 128) {
        int s = csr[s0 + i];
        float v = as1[s * 2 + h] + adn;
        v = (v >= 0.f) ? v : NEG_SLOPE * v;
        lm = fmaxf(lm, v);
    }
    red[tid] = lm;
    __syncthreads();
    for (int off = 64; off >= 1; off >>= 1) {
        if (slot < off) red[tid] = fmaxf(red[tid], red[tid + 2 * off]);
        __syncthreads();
    }
    if (tid < 2) m_s[tid] = red[tid];
    __syncthreads();
    float m = m_s[h];

    // stage 1b: sum of exp
    float ls = 0.f;
    for (int i = slot; i < deg; i += 128) {
        int s = csr[s0 + i];
        float v = as1[s * 2 + h] + adn;
        v = (v >= 0.f) ? v : NEG_SLOPE * v;
        ls += __expf(v - m);
    }
    red[tid] = ls;
    __syncthreads();
    for (int off = 64; off >= 1; off >>= 1) {
        if (slot < off) red[tid] += red[tid + 2 * off];
        __syncthreads();
    }
    if (tid < 2) rd_s[tid] = 1.f / (red[tid] + 1e-16f);
    __syncthreads();

    float m0 = m_s[0], m1 = m_s[1];
    float rd0 = rd_s[0], rd1 = rd_s[1];

    // stage 2: 8 edge-groups x 32 lanes (float4 over the 128-col row)
    int g = tid >> 5;
    int l = tid & 31;
    int headc = l >> 4;               // cols 0..63 head0, 64..127 head1
    float4 acc = make_float4(0.f, 0.f, 0.f, 0.f);
    for (int i = g; i < deg; i += 8) {
        int s = csr[s0 + i];
        float2 av = *reinterpret_cast<const float2*>(&as1[s * 2]);
        float v0 = av.x + adn0; v0 = (v0 >= 0.f) ? v0 : NEG_SLOPE * v0;
        float v1 = av.y + adn1; v1 = (v1 >= 0.f) ? v1 : NEG_SLOPE * v1;
        float p = headc ? (__expf(v1 - m1) * rd1) : (__expf(v0 - m0) * rd0);
        float4 hv = *reinterpret_cast<const float4*>(&h1[(long)s * HC1 + 4 * l]);
        acc.x = fmaf(hv.x, p, acc.x);
        acc.y = fmaf(hv.y, p, acc.y);
        acc.z = fmaf(hv.z, p, acc.z);
        acc.w = fmaf(hv.w, p, acc.w);
    }
    *reinterpret_cast<float4*>(&accs[g][4 * l]) = acc;
    __syncthreads();

    if (tid < HC1) {
        float o = 0.f;
#pragma unroll
        for (int g2 = 0; g2 < 8; ++g2) o += accs[g2][tid];
        o += b1[tid];
        h2[(long)n * HC1 + tid] = (o > 0.f) ? o : expm1f(o);   // ELU
    }
}

// ---------------------------------------------------------------------------
// Layer 2 GEMM (unchanged)
// ---------------------------------------------------------------------------
__global__ __launch_bounds__(256)
void gemm2_alpha(const float* __restrict__ h2, const float* __restrict__ W2,
                 const float* __restrict__ a_src, const float* __restrict__ a_dst,
                 float* __restrict__ z, float* __restrict__ as2, float* __restrict__ ad2,
                 int N) {
    __shared__ float hs[16][FIN + 4];
    __shared__ float ws[FIN * NCLS];
    int tid = threadIdx.x;
    int n0 = blockIdx.x * 16;
    for (int i = tid; i < FIN * NCLS; i += 256) ws[i] = W2[i];
    for (int i = tid; i < 16 * FIN; i += 256) {
        int r = i >> 7, c = i & 127;
        int n = n0 + r;
        hs[r][c] = (n < N) ? h2[(long)n * FIN + c] : 0.f;
    }
    __syncthreads();

    int r = tid >> 4, c = tid & 15;
    int n = n0 + r;
    float acc = 0.f;
#pragma unroll 4
    for (int k = 0; k < FIN; ++k)
        acc = fmaf(hs[r][k], ws[k * NCLS + c], acc);

    float sa = acc * a_src[c];
    float da = acc * a_dst[c];
    for (int off = 8; off >= 1; off >>= 1) {
        sa += __shfl_xor(sa, off, 16);
        da += __shfl_xor(da, off, 16);
    }
    if (n < N) {
        z[n * NCLS + c] = acc;
        if (c == 0) { as2[n] = sa; ad2[n] = da; }
    }
}

// ---------------------------------------------------------------------------
// Layer 2 aggregation v2: wave per node (4 nodes / 256-block).
// Lane-parallel score reduce; 16 edge-groups x 4 lanes x float4 gather;
// butterfly reduce; fused bias + log_softmax.
// ---------------------------------------------------------------------------
__global__ __launch_bounds__(256)
void aggregate2_v2(const int* __restrict__ offs, const int* __restrict__ csr,
                   const float* __restrict__ z, const float* __restrict__ as2,
                   const float* __restrict__ ad2, const float* __restrict__ b2,
                   float* __restrict__ out, int N) {
    int wid = threadIdx.x >> 6;
    int lane = threadIdx.x & 63;
    int n = blockIdx.x * 4 + wid;
    if (n >= N) return;
    int s0 = offs[n], s1 = offs[n + 1];
    int deg = s1 - s0;
    float adn = ad2[n];

    // stage 1: max, then sum(exp)
    float lm = -1e30f;
    for (int i = lane; i < deg; i += 64) {
        float v = as2[csr[s0 + i]] + adn;
        v = (v >= 0.f) ? v : NEG_SLOPE * v;
        lm = fmaxf(lm, v);
    }
    for (int off = 32; off >= 1; off >>= 1) lm = fmaxf(lm, __shfl_xor(lm, off, 64));
    float ls = 0.f;
    for (int i = lane; i < deg; i += 64) {
        float v = as2[csr[s0 + i]] + adn;
        v = (v >= 0.f) ? v : NEG_SLOPE * v;
        ls += __expf(v - lm);
    }
    for (int off = 32; off >= 1; off >>= 1) ls += __shfl_xor(ls, off, 64);
    float rden = 1.f / (ls + 1e-16f);

    // stage 2: 16 groups x 4 lanes, float4 over the 16-col row
    int g = lane >> 2, l = lane & 3;
    float4 acc = make_float4(0.f, 0.f, 0.f, 0.f);
    for (int i = g; i < deg; i += 16) {
        int s = csr[s0 + i];
        float v = as2[s] + adn;
        v = (v >= 0.f) ? v : NEG_SLOPE * v;
        float p = __expf(v - lm) * rden;
        float4 zv = *reinterpret_cast<const float4*>(&z[(long)s * NCLS + 4 * l]);
        acc.x = fmaf(zv.x, p, acc.x);
        acc.y = fmaf(zv.y, p, acc.y);
        acc.z = fmaf(zv.z, p, acc.z);
        acc.w = fmaf(zv.w, p, acc.w);
    }
    // reduce across the 16 groups (lanes with equal lane&3)
    for (int off = 4; off <= 32; off <<= 1) {
        acc.x += __shfl_xor(acc.x, off, 64);
        acc.y += __shfl_xor(acc.y, off, 64);
        acc.z += __shfl_xor(acc.z, off, 64);
        acc.w += __shfl_xor(acc.w, off, 64);
    }
    // every lane now holds the final sums for cols 4*(lane&3)..+3
    float4 o;
    o.x = acc.x + b2[4 * l + 0];
    o.y = acc.y + b2[4 * l + 1];
    o.z = acc.z + b2[4 * l + 2];
    o.w = acc.w + b2[4 * l + 3];

    // log_softmax across 16 classes (4 lanes x 4 comps)
    float mx = fmaxf(fmaxf(o.x, o.y), fmaxf(o.z, o.w));
    mx = fmaxf(mx, __shfl_xor(mx, 1, 64));
    mx = fmaxf(mx, __shfl_xor(mx, 2, 64));
    float ex = __expf(o.x - mx) + __expf(o.y - mx) + __expf(o.z - mx) + __expf(o.w - mx);
    ex += __shfl_xor(ex, 1, 64);
    ex += __shfl_xor(ex, 2, 64);
    float lse = mx + __logf(ex);

    if (lane < 4) {
        float4 r;
        r.x = o.x - lse; r.y = o.y - lse; r.z = o.z - lse; r.w = o.w - lse;
        *reinterpret_cast<float4*>(&out[(long)n * NCLS + 4 * l]) = r;
    }
}

// ---------------------------------------------------------------------------
extern "C" void kernel_launch(void* const* d_in, const int* in_sizes, int n_in,
                              void* d_out, int out_size, void* d_ws, size_t ws_size,
                              hipStream_t stream) {
    const float* x        = (const float*)d_in[0];
    const int*   ei       = (const int*)  d_in[1];
    // d_in[2] = edge_attr (unused by reference)
    const float* W1       = (const float*)d_in[3];
    const float* att_src1 = (const float*)d_in[4];
    const float* att_dst1 = (const float*)d_in[5];
    const float* b1       = (const float*)d_in[6];
    const float* W2       = (const float*)d_in[7];
    const float* att_src2 = (const float*)d_in[8];
    const float* att_dst2 = (const float*)d_in[9];
    const float* b2       = (const float*)d_in[10];
    float* out = (float*)d_out;

    const int N = in_sizes[0] / FIN;        // 50000
    const int E = in_sizes[1] / 2;          // 800000
    const int Etot = E + N;                 // self-loops appended

    // Workspace layout (bytes)
    char* ws = (char*)d_ws;
    size_t off = 0;
    auto alloc = [&](size_t bytes) { char* p = ws + off; off += (bytes + 255) & ~(size_t)255; return p; };
    int*   cnt    = (int*)  alloc((size_t)N * 4);
    int*   offs   = (int*)  alloc((size_t)(N + 1) * 4);
    int*   cursor = (int*)  alloc((size_t)N * 4);
    int*   csr    = (int*)  alloc((size_t)Etot * 4);
    float* h1     = (float*)alloc((size_t)N * HC1 * 4);
    float* h2     = (float*)alloc((size_t)N * HC1 * 4);
    float* z      = (float*)alloc((size_t)N * NCLS * 4);
    float* as1    = (float*)alloc((size_t)N * 2 * 4);
    float* ad1    = (float*)alloc((size_t)N * 2 * 4);
    float* as2    = (float*)alloc((size_t)N * 4);
    float* ad2    = (float*)alloc((size_t)N * 4);
    (void)ws_size;

    hipMemsetAsync(cnt, 0, (size_t)N * 4, stream);

    int tb = 256;
    int eb = (Etot + tb - 1) / tb;
    hist_kernel<<<eb, tb, 0, stream>>>(ei, cnt, E, N);
    scan_kernel<<<1, 1024, 0, stream>>>(cnt, offs, cursor, N);
    scatter_kernel<<<eb, tb, 0, stream>>>(ei, cursor, csr, E, N);

    gemm1_alpha<<<(N + NPB1 - 1) / NPB1, 128, 0, stream>>>(
        x, W1, att_src1, att_dst1, h1, as1, ad1, N);
    aggregate1_v2<<<N, 256, 0, stream>>>(offs, csr, h1, as1, ad1, b1, h2, N);
    gemm2_alpha<<<(N + 15) / 16, 256, 0, stream>>>(
        h2, W2, att_src2, att_dst2, z, as2, ad2, N);
    aggregate2_v2<<<(N + 3) / 4, 256, 0, stream>>>(offs, csr, z, as2, ad2, b2, out, N);
}

// Round 3
// 382.989 us; speedup vs baseline: 1.2342x; 1.2051x over previous
//
#include <hip/hip_runtime.h>
#include <math.h>

// Problem constants (match reference)
#define FIN   128
#define HC1   128   // H*C for layer 1
#define NCLS  16
#define NEG_SLOPE 0.2f

// ---------------------------------------------------------------------------
// CSR build kernels (dst -> incoming edge list), shared by both layers
// ---------------------------------------------------------------------------
__global__ void hist_kernel(const int* __restrict__ ei, int* __restrict__ cnt,
                            int E, int N) {
    int e = blockIdx.x * blockDim.x + threadIdx.x;
    int tot = E + N;
    if (e >= tot) return;
    int d = (e < E) ? ei[E + e] : (e - E);   // self-loop dst = node id
    atomicAdd(&cnt[d], 1);
}

__global__ __launch_bounds__(1024)
void scan_kernel(const int* __restrict__ cnt, int* __restrict__ offs,
                 int* __restrict__ cursor, int N) {
    __shared__ int lds[1024];
    int t = threadIdx.x;
    const int CH = (N + 1023) / 1024;
    int base = t * CH;
    int local = 0;
    for (int j = 0; j < CH; ++j) {
        int i = base + j;
        if (i < N) local += cnt[i];
    }
    lds[t] = local;
    __syncthreads();
    for (int off = 1; off < 1024; off <<= 1) {
        int v = (t >= off) ? lds[t - off] : 0;
        __syncthreads();
        lds[t] += v;
        __syncthreads();
    }
    int run = lds[t] - local;   // exclusive prefix
    for (int j = 0; j < CH; ++j) {
        int i = base + j;
        if (i < N) {
            offs[i] = run;
            cursor[i] = run;
            run += cnt[i];
        }
    }
    if (t == 1023) offs[N] = lds[1023];
}

__global__ void scatter_kernel(const int* __restrict__ ei, int* __restrict__ cursor,
                               int* __restrict__ csr_src, int E, int N) {
    int e = blockIdx.x * blockDim.x + threadIdx.x;
    int tot = E + N;
    if (e >= tot) return;
    int d, s;
    if (e < E) { d = ei[E + e]; s = ei[e]; }
    else       { d = e - E;     s = e - E; }
    int pos = atomicAdd(&cursor[d], 1);
    csr_src[pos] = s;
}

// ---------------------------------------------------------------------------
// Layer 1 GEMM: h1[N][128] = x @ W1 + fused alpha scalars (unchanged)
// ---------------------------------------------------------------------------
#define NPB1 16
__global__ __launch_bounds__(128)
void gemm1_alpha(const float* __restrict__ x, const float* __restrict__ W,
                 const float* __restrict__ a_src, const float* __restrict__ a_dst,
                 float* __restrict__ h1, float* __restrict__ as1, float* __restrict__ ad1,
                 int N) {
    __shared__ float xs[NPB1][FIN];
    int tid = threadIdx.x;          // output column 0..127 (head = tid>>6)
    int n0 = blockIdx.x * NPB1;
    for (int r = 0; r < NPB1; ++r) {
        int n = n0 + r;
        xs[r][tid] = (n < N) ? x[(long)n * FIN + tid] : 0.f;
    }
    __syncthreads();

    float acc[NPB1];
#pragma unroll
    for (int r = 0; r < NPB1; ++r) acc[r] = 0.f;

    for (int k = 0; k < FIN; k += 4) {
        float w0 = W[(k + 0) * HC1 + tid];
        float w1 = W[(k + 1) * HC1 + tid];
        float w2 = W[(k + 2) * HC1 + tid];
        float w3 = W[(k + 3) * HC1 + tid];
#pragma unroll
        for (int r = 0; r < NPB1; ++r) {
            float4 xv = *reinterpret_cast<const float4*>(&xs[r][k]);
            acc[r] = fmaf(xv.x, w0, acc[r]);
            acc[r] = fmaf(xv.y, w1, acc[r]);
            acc[r] = fmaf(xv.z, w2, acc[r]);
            acc[r] = fmaf(xv.w, w3, acc[r]);
        }
    }

    float av_s = a_src[tid];
    float av_d = a_dst[tid];
    int head = tid >> 6;
#pragma unroll
    for (int r = 0; r < NPB1; ++r) {
        int n = n0 + r;
        if (n >= N) break;
        h1[(long)n * HC1 + tid] = acc[r];
        float s = acc[r] * av_s;
        float d = acc[r] * av_d;
        for (int off = 32; off >= 1; off >>= 1) {
            s += __shfl_down(s, off, 64);
            d += __shfl_down(d, off, 64);
        }
        if ((tid & 63) == 0) {
            as1[n * 2 + head] = s;
            ad1[n * 2 + head] = d;
        }
    }
}

// ---------------------------------------------------------------------------
// Layer 1 scores: 16 lanes per node, no barriers/atomics.
// Writes unnormalized p per edge (CSR order) and 1/denominator per node.
// ---------------------------------------------------------------------------
__global__ __launch_bounds__(256)
void scores1(const int* __restrict__ offs, const int* __restrict__ csr,
             const float* __restrict__ as_arr, const float* __restrict__ ad_arr,
             float2* __restrict__ pe, float2* __restrict__ rden, int N) {
    int n = (blockIdx.x * blockDim.x + threadIdx.x) >> 4;
    int l = threadIdx.x & 15;
    if (n >= N) return;
    int s0 = offs[n], s1 = offs[n + 1];
    float ad0 = ad_arr[2 * n], ad1v = ad_arr[2 * n + 1];

    float m0 = -1e30f, m1 = -1e30f;
    for (int i = s0 + l; i < s1; i += 16) {
        int s = csr[i];
        float2 a = *reinterpret_cast<const float2*>(&as_arr[2 * s]);
        float v0 = a.x + ad0; v0 = (v0 >= 0.f) ? v0 : NEG_SLOPE * v0;
        float v1 = a.y + ad1v; v1 = (v1 >= 0.f) ? v1 : NEG_SLOPE * v1;
        m0 = fmaxf(m0, v0); m1 = fmaxf(m1, v1);
    }
#pragma unroll
    for (int off = 8; off >= 1; off >>= 1) {
        m0 = fmaxf(m0, __shfl_xor(m0, off, 16));
        m1 = fmaxf(m1, __shfl_xor(m1, off, 16));
    }
    float d0 = 0.f, d1 = 0.f;
    for (int i = s0 + l; i < s1; i += 16) {
        int s = csr[i];
        float2 a = *reinterpret_cast<const float2*>(&as_arr[2 * s]);
        float v0 = a.x + ad0; v0 = (v0 >= 0.f) ? v0 : NEG_SLOPE * v0;
        float v1 = a.y + ad1v; v1 = (v1 >= 0.f) ? v1 : NEG_SLOPE * v1;
        float p0 = __expf(v0 - m0), p1 = __expf(v1 - m1);
        d0 += p0; d1 += p1;
        pe[i] = make_float2(p0, p1);
    }
#pragma unroll
    for (int off = 8; off >= 1; off >>= 1) {
        d0 += __shfl_xor(d0, off, 16);
        d1 += __shfl_xor(d1, off, 16);
    }
    if (l == 0) rden[n] = make_float2(1.f / (d0 + 1e-16f), 1.f / (d1 + 1e-16f));
}

// ---------------------------------------------------------------------------
// Layer 1 gather: pure SpMM h2[n] = (sum_e p_e * h1[src_e]) * rden + b1, ELU.
// 32 lanes x float4 per node (one 512B row per load), 8 nodes per 256-block,
// edge loop unrolled x4, zero barriers.
// ---------------------------------------------------------------------------
__global__ __launch_bounds__(256)
void gather1(const int* __restrict__ offs, const int* __restrict__ csr,
             const float2* __restrict__ pe, const float2* __restrict__ rden,
             const float* __restrict__ h1, const float* __restrict__ b1,
             float* __restrict__ h2, int N) {
    int g = threadIdx.x >> 5;        // 0..7 node-group in block
    int l = threadIdx.x & 31;        // lane in group: cols 4l..4l+3
    int n = blockIdx.x * 8 + g;
    if (n >= N) return;
    int head = l >> 4;
    int s0 = offs[n], s1 = offs[n + 1];

    float4 acc = make_float4(0.f, 0.f, 0.f, 0.f);
    int i = s0;
    for (; i + 4 <= s1; i += 4) {
        int sa = csr[i], sb = csr[i + 1], sc = csr[i + 2], sd = csr[i + 3];
        float2 pa = pe[i], pb = pe[i + 1], pc = pe[i + 2], pd = pe[i + 3];
        float4 ha = *reinterpret_cast<const float4*>(&h1[((long)sa << 7) + 4 * l]);
        float4 hb = *reinterpret_cast<const float4*>(&h1[((long)sb << 7) + 4 * l]);
        float4 hc = *reinterpret_cast<const float4*>(&h1[((long)sc << 7) + 4 * l]);
        float4 hd = *reinterpret_cast<const float4*>(&h1[((long)sd << 7) + 4 * l]);
        float wa = head ? pa.y : pa.x;
        float wb = head ? pb.y : pb.x;
        float wc = head ? pc.y : pc.x;
        float wd = head ? pd.y : pd.x;
        acc.x = fmaf(ha.x, wa, acc.x); acc.y = fmaf(ha.y, wa, acc.y);
        acc.z = fmaf(ha.z, wa, acc.z); acc.w = fmaf(ha.w, wa, acc.w);
        acc.x = fmaf(hb.x, wb, acc.x); acc.y = fmaf(hb.y, wb, acc.y);
        acc.z = fmaf(hb.z, wb, acc.z); acc.w = fmaf(hb.w, wb, acc.w);
        acc.x = fmaf(hc.x, wc, acc.x); acc.y = fmaf(hc.y, wc, acc.y);
        acc.z = fmaf(hc.z, wc, acc.z); acc.w = fmaf(hc.w, wc, acc.w);
        acc.x = fmaf(hd.x, wd, acc.x); acc.y = fmaf(hd.y, wd, acc.y);
        acc.z = fmaf(hd.z, wd, acc.z); acc.w = fmaf(hd.w, wd, acc.w);
    }
    for (; i < s1; ++i) {
        int s = csr[i];
        float2 p2 = pe[i];
        float w = head ? p2.y : p2.x;
        float4 hv = *reinterpret_cast<const float4*>(&h1[((long)s << 7) + 4 * l]);
        acc.x = fmaf(hv.x, w, acc.x); acc.y = fmaf(hv.y, w, acc.y);
        acc.z = fmaf(hv.z, w, acc.z); acc.w = fmaf(hv.w, w, acc.w);
    }
    float2 rd = rden[n];
    float r = head ? rd.y : rd.x;
    int col = 4 * l;
    float4 bb = *reinterpret_cast<const float4*>(&b1[col]);
    float4 o;
    o.x = acc.x * r + bb.x; o.y = acc.y * r + bb.y;
    o.z = acc.z * r + bb.z; o.w = acc.w * r + bb.w;
    o.x = (o.x > 0.f) ? o.x : expm1f(o.x);
    o.y = (o.y > 0.f) ? o.y : expm1f(o.y);
    o.z = (o.z > 0.f) ? o.z : expm1f(o.z);
    o.w = (o.w > 0.f) ? o.w : expm1f(o.w);
    *reinterpret_cast<float4*>(&h2[((long)n << 7) + col]) = o;
}

// ---------------------------------------------------------------------------
// Layer 2 GEMM (unchanged)
// ---------------------------------------------------------------------------
__global__ __launch_bounds__(256)
void gemm2_alpha(const float* __restrict__ h2, const float* __restrict__ W2,
                 const float* __restrict__ a_src, const float* __restrict__ a_dst,
                 float* __restrict__ z, float* __restrict__ as2, float* __restrict__ ad2,
                 int N) {
    __shared__ float hs[16][FIN + 4];
    __shared__ float ws[FIN * NCLS];
    int tid = threadIdx.x;
    int n0 = blockIdx.x * 16;
    for (int i = tid; i < FIN * NCLS; i += 256) ws[i] = W2[i];
    for (int i = tid; i < 16 * FIN; i += 256) {
        int r = i >> 7, c = i & 127;
        int n = n0 + r;
        hs[r][c] = (n < N) ? h2[(long)n * FIN + c] : 0.f;
    }
    __syncthreads();

    int r = tid >> 4, c = tid & 15;
    int n = n0 + r;
    float acc = 0.f;
#pragma unroll 4
    for (int k = 0; k < FIN; ++k)
        acc = fmaf(hs[r][k], ws[k * NCLS + c], acc);

    float sa = acc * a_src[c];
    float da = acc * a_dst[c];
    for (int off = 8; off >= 1; off >>= 1) {
        sa += __shfl_xor(sa, off, 16);
        da += __shfl_xor(da, off, 16);
    }
    if (n < N) {
        z[n * NCLS + c] = acc;
        if (c == 0) { as2[n] = sa; ad2[n] = da; }
    }
}

// ---------------------------------------------------------------------------
// Layer 2 scores (H=1): 16 lanes per node, writes pe2 (CSR order) + rden2.
// ---------------------------------------------------------------------------
__global__ __launch_bounds__(256)
void scores2(const int* __restrict__ offs, const int* __restrict__ csr,
             const float* __restrict__ as2, const float* __restrict__ ad2,
             float* __restrict__ pe2, float* __restrict__ rden2, int N) {
    int n = (blockIdx.x * blockDim.x + threadIdx.x) >> 4;
    int l = threadIdx.x & 15;
    if (n >= N) return;
    int s0 = offs[n], s1 = offs[n + 1];
    float adn = ad2[n];

    float m = -1e30f;
    for (int i = s0 + l; i < s1; i += 16) {
        float v = as2[csr[i]] + adn;
        v = (v >= 0.f) ? v : NEG_SLOPE * v;
        m = fmaxf(m, v);
    }
#pragma unroll
    for (int off = 8; off >= 1; off >>= 1) m = fmaxf(m, __shfl_xor(m, off, 16));
    float d = 0.f;
    for (int i = s0 + l; i < s1; i += 16) {
        float v = as2[csr[i]] + adn;
        v = (v >= 0.f) ? v : NEG_SLOPE * v;
        float p = __expf(v - m);
        d += p;
        pe2[i] = p;
    }
#pragma unroll
    for (int off = 8; off >= 1; off >>= 1) d += __shfl_xor(d, off, 16);
    if (l == 0) rden2[n] = 1.f / (d + 1e-16f);
}

// ---------------------------------------------------------------------------
// Layer 2 gather + bias + log_softmax. 16 lanes per node (lane = class),
// 16 nodes per 256-block, unrolled x4, no barriers.
// ---------------------------------------------------------------------------
__global__ __launch_bounds__(256)
void gather2(const int* __restrict__ offs, const int* __restrict__ csr,
             const float* __restrict__ pe2, const float* __restrict__ rden2,
             const float* __restrict__ z, const float* __restrict__ b2,
             float* __restrict__ out, int N) {
    int g = threadIdx.x >> 4;
    int l = threadIdx.x & 15;
    int n = blockIdx.x * 16 + g;
    if (n >= N) return;
    int s0 = offs[n], s1 = offs[n + 1];

    float acc = 0.f;
    int i = s0;
    for (; i + 4 <= s1; i += 4) {
        int sa = csr[i], sb = csr[i + 1], sc = csr[i + 2], sd = csr[i + 3];
        float pa = pe2[i], pb = pe2[i + 1], pc = pe2[i + 2], pd = pe2[i + 3];
        float za = z[sa * NCLS + l];
        float zb = z[sb * NCLS + l];
        float zc = z[sc * NCLS + l];
        float zd = z[sd * NCLS + l];
        acc = fmaf(za, pa, acc);
        acc = fmaf(zb, pb, acc);
        acc = fmaf(zc, pc, acc);
        acc = fmaf(zd, pd, acc);
    }
    for (; i < s1; ++i) acc = fmaf(z[csr[i] * NCLS + l], pe2[i], acc);

    float o = acc * rden2[n] + b2[l];

    float mx = o;
#pragma unroll
    for (int off = 8; off >= 1; off >>= 1) mx = fmaxf(mx, __shfl_xor(mx, off, 16));
    float ex = __expf(o - mx);
    float sum = ex;
#pragma unroll
    for (int off = 8; off >= 1; off >>= 1) sum += __shfl_xor(sum, off, 16);
    out[(long)n * NCLS + l] = o - mx - __logf(sum);
}

// ---------------------------------------------------------------------------
extern "C" void kernel_launch(void* const* d_in, const int* in_sizes, int n_in,
                              void* d_out, int out_size, void* d_ws, size_t ws_size,
                              hipStream_t stream) {
    const float* x        = (const float*)d_in[0];
    const int*   ei       = (const int*)  d_in[1];
    // d_in[2] = edge_attr (unused by reference)
    const float* W1       = (const float*)d_in[3];
    const float* att_src1 = (const float*)d_in[4];
    const float* att_dst1 = (const float*)d_in[5];
    const float* b1       = (const float*)d_in[6];
    const float* W2       = (const float*)d_in[7];
    const float* att_src2 = (const float*)d_in[8];
    const float* att_dst2 = (const float*)d_in[9];
    const float* b2       = (const float*)d_in[10];
    float* out = (float*)d_out;

    const int N = in_sizes[0] / FIN;        // 50000
    const int E = in_sizes[1] / 2;          // 800000
    const int Etot = E + N;                 // self-loops appended

    // Workspace layout (bytes), with aliasing for layer-2 temporaries
    char* ws = (char*)d_ws;
    size_t off = 0;
    auto alloc = [&](size_t bytes) { char* p = ws + off; off += (bytes + 255) & ~(size_t)255; return p; };
    int*    cnt    = (int*)   alloc((size_t)N * 4);
    int*    offs   = (int*)   alloc((size_t)(N + 1) * 4);
    int*    cursor = (int*)   alloc((size_t)N * 4);
    int*    csr    = (int*)   alloc((size_t)Etot * 4);
    float*  h1     = (float*) alloc((size_t)N * HC1 * 4);   // layer2: z aliases h1
    float*  h2     = (float*) alloc((size_t)N * HC1 * 4);
    float2* pe     = (float2*)alloc((size_t)Etot * 8);      // layer2: pe2 aliases pe
    float2* rden   = (float2*)alloc((size_t)N * 8);         // layer2: rden2 aliases
    float*  as1    = (float*) alloc((size_t)N * 2 * 4);     // layer2: as2 aliases
    float*  ad1    = (float*) alloc((size_t)N * 2 * 4);     // layer2: ad2 aliases
    (void)ws_size;

    float* z     = h1;            // safe: gather1 (reads h1) precedes gemm2 (writes z)
    float* pe2   = (float*)pe;    // safe: gather1 (reads pe) precedes scores2
    float* rden2 = (float*)rden;
    float* as2   = as1;
    float* ad2   = ad1;

    hipMemsetAsync(cnt, 0, (size_t)N * 4, stream);

    int tb = 256;
    int eb = (Etot + tb - 1) / tb;
    hist_kernel<<<eb, tb, 0, stream>>>(ei, cnt, E, N);
    scan_kernel<<<1, 1024, 0, stream>>>(cnt, offs, cursor, N);
    scatter_kernel<<<eb, tb, 0, stream>>>(ei, cursor, csr, E, N);

    gemm1_alpha<<<(N + NPB1 - 1) / NPB1, 128, 0, stream>>>(
        x, W1, att_src1, att_dst1, h1, as1, ad1, N);
    scores1<<<(N + 15) / 16, 256, 0, stream>>>(offs, csr, as1, ad1, pe, rden, N);
    gather1<<<(N + 7) / 8, 256, 0, stream>>>(offs, csr, pe, rden, h1, b1, h2, N);

    gemm2_alpha<<<(N + 15) / 16, 256, 0, stream>>>(
        h2, W2, att_src2, att_dst2, z, as2, ad2, N);
    scores2<<<(N + 15) / 16, 256, 0, stream>>>(offs, csr, as2, ad2, pe2, rden2, N);
    gather2<<<(N + 15) / 16, 256, 0, stream>>>(offs, csr, pe2, rden2, z, b2, out, N);
}

// Round 4
// 269.477 us; speedup vs baseline: 1.7541x; 1.4212x over previous
//
#include <hip/hip_runtime.h>
#include <math.h>

// Problem constants (match reference)
#define FIN   128
#define HC1   128   // H*C for layer 1
#define NCLS  16
#define NEG_SLOPE 0.2f

// ---------------------------------------------------------------------------
// CSR build kernels (dst -> incoming edge list), shared by both layers
// ---------------------------------------------------------------------------
__global__ void hist_kernel(const int* __restrict__ ei, int* __restrict__ cnt,
                            int E, int N) {
    int e = blockIdx.x * blockDim.x + threadIdx.x;
    int tot = E + N;
    if (e >= tot) return;
    int d = (e < E) ? ei[E + e] : (e - E);   // self-loop dst = node id
    atomicAdd(&cnt[d], 1);
}

// ---- 3-phase device-wide exclusive scan over cnt[N] -> offs/cursor ----
#define SCB 256   // scan block size == elements per block

__global__ __launch_bounds__(SCB)
void scan_partial(const int* __restrict__ cnt, int* __restrict__ bsum, int N) {
    __shared__ int lds[SCB];
    int b = blockIdx.x, t = threadIdx.x;
    int i = b * SCB + t;
    int v = (i < N) ? cnt[i] : 0;
    lds[t] = v;
    __syncthreads();
    for (int off = SCB / 2; off >= 1; off >>= 1) {
        if (t < off) lds[t] += lds[t + off];
        __syncthreads();
    }
    if (t == 0) bsum[b] = lds[0];
}

__global__ __launch_bounds__(SCB)
void scan_top(int* __restrict__ bsum, int* __restrict__ base, int nb) {
    __shared__ int lds[SCB];
    int t = threadIdx.x;
    int v = (t < nb) ? bsum[t] : 0;
    lds[t] = v;
    __syncthreads();
    for (int off = 1; off < SCB; off <<= 1) {
        int u = (t >= off) ? lds[t - off] : 0;
        __syncthreads();
        lds[t] += u;
        __syncthreads();
    }
    if (t < nb) base[t] = lds[t] - v;   // exclusive
}

__global__ __launch_bounds__(SCB)
void scan_bottom(const int* __restrict__ cnt, const int* __restrict__ base,
                 int* __restrict__ offs, int* __restrict__ cursor, int N) {
    __shared__ int lds[SCB];
    int b = blockIdx.x, t = threadIdx.x;
    int i = b * SCB + t;
    int v = (i < N) ? cnt[i] : 0;
    lds[t] = v;
    __syncthreads();
    for (int off = 1; off < SCB; off <<= 1) {
        int u = (t >= off) ? lds[t - off] : 0;
        __syncthreads();
        lds[t] += u;
        __syncthreads();
    }
    int excl = base[b] + lds[t] - v;
    if (i < N) { offs[i] = excl; cursor[i] = excl; }
    if (i == N - 1) offs[N] = excl + v;
}

__global__ void scatter_kernel(const int* __restrict__ ei, int* __restrict__ cursor,
                               int* __restrict__ csr_src, int E, int N) {
    int e = blockIdx.x * blockDim.x + threadIdx.x;
    int tot = E + N;
    if (e >= tot) return;
    int d, s;
    if (e < E) { d = ei[E + e]; s = ei[e]; }
    else       { d = e - E;     s = e - E; }
    int pos = atomicAdd(&cursor[d], 1);
    csr_src[pos] = s;
}

// ---------------------------------------------------------------------------
// Layer 1 GEMM: h1[N][128] = x @ W1 + fused alpha scalars
// ---------------------------------------------------------------------------
#define NPB1 16
__global__ __launch_bounds__(128)
void gemm1_alpha(const float* __restrict__ x, const float* __restrict__ W,
                 const float* __restrict__ a_src, const float* __restrict__ a_dst,
                 float* __restrict__ h1, float* __restrict__ as1, float* __restrict__ ad1,
                 int N) {
    __shared__ float xs[NPB1][FIN];
    int tid = threadIdx.x;          // output column 0..127 (head = tid>>6)
    int n0 = blockIdx.x * NPB1;
    for (int r = 0; r < NPB1; ++r) {
        int n = n0 + r;
        xs[r][tid] = (n < N) ? x[(long)n * FIN + tid] : 0.f;
    }
    __syncthreads();

    float acc[NPB1];
#pragma unroll
    for (int r = 0; r < NPB1; ++r) acc[r] = 0.f;

    for (int k = 0; k < FIN; k += 4) {
        float w0 = W[(k + 0) * HC1 + tid];
        float w1 = W[(k + 1) * HC1 + tid];
        float w2 = W[(k + 2) * HC1 + tid];
        float w3 = W[(k + 3) * HC1 + tid];
#pragma unroll
        for (int r = 0; r < NPB1; ++r) {
            float4 xv = *reinterpret_cast<const float4*>(&xs[r][k]);
            acc[r] = fmaf(xv.x, w0, acc[r]);
            acc[r] = fmaf(xv.y, w1, acc[r]);
            acc[r] = fmaf(xv.z, w2, acc[r]);
            acc[r] = fmaf(xv.w, w3, acc[r]);
        }
    }

    float av_s = a_src[tid];
    float av_d = a_dst[tid];
    int head = tid >> 6;
#pragma unroll
    for (int r = 0; r < NPB1; ++r) {
        int n = n0 + r;
        if (n >= N) break;
        h1[(long)n * HC1 + tid] = acc[r];
        float s = acc[r] * av_s;
        float d = acc[r] * av_d;
        for (int off = 32; off >= 1; off >>= 1) {
            s += __shfl_down(s, off, 64);
            d += __shfl_down(d, off, 64);
        }
        if ((tid & 63) == 0) {
            as1[n * 2 + head] = s;
            ad1[n * 2 + head] = d;
        }
    }
}

// ---------------------------------------------------------------------------
// Layer 1 scores: 16 lanes per node, no barriers/atomics.
// ---------------------------------------------------------------------------
__global__ __launch_bounds__(256)
void scores1(const int* __restrict__ offs, const int* __restrict__ csr,
             const float* __restrict__ as_arr, const float* __restrict__ ad_arr,
             float2* __restrict__ pe, float2* __restrict__ rden, int N) {
    int n = (blockIdx.x * blockDim.x + threadIdx.x) >> 4;
    int l = threadIdx.x & 15;
    if (n >= N) return;
    int s0 = offs[n], s1 = offs[n + 1];
    float ad0 = ad_arr[2 * n], ad1v = ad_arr[2 * n + 1];

    float m0 = -1e30f, m1 = -1e30f;
    for (int i = s0 + l; i < s1; i += 16) {
        int s = csr[i];
        float2 a = *reinterpret_cast<const float2*>(&as_arr[2 * s]);
        float v0 = a.x + ad0; v0 = (v0 >= 0.f) ? v0 : NEG_SLOPE * v0;
        float v1 = a.y + ad1v; v1 = (v1 >= 0.f) ? v1 : NEG_SLOPE * v1;
        m0 = fmaxf(m0, v0); m1 = fmaxf(m1, v1);
    }
#pragma unroll
    for (int off = 8; off >= 1; off >>= 1) {
        m0 = fmaxf(m0, __shfl_xor(m0, off, 16));
        m1 = fmaxf(m1, __shfl_xor(m1, off, 16));
    }
    float d0 = 0.f, d1 = 0.f;
    for (int i = s0 + l; i < s1; i += 16) {
        int s = csr[i];
        float2 a = *reinterpret_cast<const float2*>(&as_arr[2 * s]);
        float v0 = a.x + ad0; v0 = (v0 >= 0.f) ? v0 : NEG_SLOPE * v0;
        float v1 = a.y + ad1v; v1 = (v1 >= 0.f) ? v1 : NEG_SLOPE * v1;
        float p0 = __expf(v0 - m0), p1 = __expf(v1 - m1);
        d0 += p0; d1 += p1;
        pe[i] = make_float2(p0, p1);
    }
#pragma unroll
    for (int off = 8; off >= 1; off >>= 1) {
        d0 += __shfl_xor(d0, off, 16);
        d1 += __shfl_xor(d1, off, 16);
    }
    if (l == 0) rden[n] = make_float2(1.f / (d0 + 1e-16f), 1.f / (d1 + 1e-16f));
}

// ---------------------------------------------------------------------------
// Layer 1 gather: pure SpMM, 32 lanes x float4 per node, 8 nodes/block,
// unrolled x4, zero barriers. Fused *rden + b1 + ELU epilogue.
// ---------------------------------------------------------------------------
__global__ __launch_bounds__(256)
void gather1(const int* __restrict__ offs, const int* __restrict__ csr,
             const float2* __restrict__ pe, const float2* __restrict__ rden,
             const float* __restrict__ h1, const float* __restrict__ b1,
             float* __restrict__ h2, int N) {
    int g = threadIdx.x >> 5;        // 0..7 node-group in block
    int l = threadIdx.x & 31;        // lane in group: cols 4l..4l+3
    int n = blockIdx.x * 8 + g;
    if (n >= N) return;
    int head = l >> 4;
    int s0 = offs[n], s1 = offs[n + 1];

    float4 acc = make_float4(0.f, 0.f, 0.f, 0.f);
    int i = s0;
    for (; i + 4 <= s1; i += 4) {
        int sa = csr[i], sb = csr[i + 1], sc = csr[i + 2], sd = csr[i + 3];
        float2 pa = pe[i], pb = pe[i + 1], pc = pe[i + 2], pd = pe[i + 3];
        float4 ha = *reinterpret_cast<const float4*>(&h1[((long)sa << 7) + 4 * l]);
        float4 hb = *reinterpret_cast<const float4*>(&h1[((long)sb << 7) + 4 * l]);
        float4 hc = *reinterpret_cast<const float4*>(&h1[((long)sc << 7) + 4 * l]);
        float4 hd = *reinterpret_cast<const float4*>(&h1[((long)sd << 7) + 4 * l]);
        float wa = head ? pa.y : pa.x;
        float wb = head ? pb.y : pb.x;
        float wc = head ? pc.y : pc.x;
        float wd = head ? pd.y : pd.x;
        acc.x = fmaf(ha.x, wa, acc.x); acc.y = fmaf(ha.y, wa, acc.y);
        acc.z = fmaf(ha.z, wa, acc.z); acc.w = fmaf(ha.w, wa, acc.w);
        acc.x = fmaf(hb.x, wb, acc.x); acc.y = fmaf(hb.y, wb, acc.y);
        acc.z = fmaf(hb.z, wb, acc.z); acc.w = fmaf(hb.w, wb, acc.w);
        acc.x = fmaf(hc.x, wc, acc.x); acc.y = fmaf(hc.y, wc, acc.y);
        acc.z = fmaf(hc.z, wc, acc.z); acc.w = fmaf(hc.w, wc, acc.w);
        acc.x = fmaf(hd.x, wd, acc.x); acc.y = fmaf(hd.y, wd, acc.y);
        acc.z = fmaf(hd.z, wd, acc.z); acc.w = fmaf(hd.w, wd, acc.w);
    }
    for (; i < s1; ++i) {
        int s = csr[i];
        float2 p2 = pe[i];
        float w = head ? p2.y : p2.x;
        float4 hv = *reinterpret_cast<const float4*>(&h1[((long)s << 7) + 4 * l]);
        acc.x = fmaf(hv.x, w, acc.x); acc.y = fmaf(hv.y, w, acc.y);
        acc.z = fmaf(hv.z, w, acc.z); acc.w = fmaf(hv.w, w, acc.w);
    }
    float2 rd = rden[n];
    float r = head ? rd.y : rd.x;
    int col = 4 * l;
    float4 bb = *reinterpret_cast<const float4*>(&b1[col]);
    float4 o;
    o.x = acc.x * r + bb.x; o.y = acc.y * r + bb.y;
    o.z = acc.z * r + bb.z; o.w = acc.w * r + bb.w;
    o.x = (o.x > 0.f) ? o.x : expm1f(o.x);
    o.y = (o.y > 0.f) ? o.y : expm1f(o.y);
    o.z = (o.z > 0.f) ? o.z : expm1f(o.z);
    o.w = (o.w > 0.f) ? o.w : expm1f(o.w);
    *reinterpret_cast<float4*>(&h2[((long)n << 7) + col]) = o;
}

// ---------------------------------------------------------------------------
// Layer 2 GEMM
// ---------------------------------------------------------------------------
__global__ __launch_bounds__(256)
void gemm2_alpha(const float* __restrict__ h2, const float* __restrict__ W2,
                 const float* __restrict__ a_src, const float* __restrict__ a_dst,
                 float* __restrict__ z, float* __restrict__ as2, float* __restrict__ ad2,
                 int N) {
    __shared__ float hs[16][FIN + 4];
    __shared__ float ws[FIN * NCLS];
    int tid = threadIdx.x;
    int n0 = blockIdx.x * 16;
    for (int i = tid; i < FIN * NCLS; i += 256) ws[i] = W2[i];
    for (int i = tid; i < 16 * FIN; i += 256) {
        int r = i >> 7, c = i & 127;
        int n = n0 + r;
        hs[r][c] = (n < N) ? h2[(long)n * FIN + c] : 0.f;
    }
    __syncthreads();

    int r = tid >> 4, c = tid & 15;
    int n = n0 + r;
    float acc = 0.f;
#pragma unroll 4
    for (int k = 0; k < FIN; ++k)
        acc = fmaf(hs[r][k], ws[k * NCLS + c], acc);

    float sa = acc * a_src[c];
    float da = acc * a_dst[c];
    for (int off = 8; off >= 1; off >>= 1) {
        sa += __shfl_xor(sa, off, 16);
        da += __shfl_xor(da, off, 16);
    }
    if (n < N) {
        z[n * NCLS + c] = acc;
        if (c == 0) { as2[n] = sa; ad2[n] = da; }
    }
}

// ---------------------------------------------------------------------------
// Layer 2 scores (H=1): 16 lanes per node.
// ---------------------------------------------------------------------------
__global__ __launch_bounds__(256)
void scores2(const int* __restrict__ offs, const int* __restrict__ csr,
             const float* __restrict__ as2, const float* __restrict__ ad2,
             float* __restrict__ pe2, float* __restrict__ rden2, int N) {
    int n = (blockIdx.x * blockDim.x + threadIdx.x) >> 4;
    int l = threadIdx.x & 15;
    if (n >= N) return;
    int s0 = offs[n], s1 = offs[n + 1];
    float adn = ad2[n];

    float m = -1e30f;
    for (int i = s0 + l; i < s1; i += 16) {
        float v = as2[csr[i]] + adn;
        v = (v >= 0.f) ? v : NEG_SLOPE * v;
        m = fmaxf(m, v);
    }
#pragma unroll
    for (int off = 8; off >= 1; off >>= 1) m = fmaxf(m, __shfl_xor(m, off, 16));
    float d = 0.f;
    for (int i = s0 + l; i < s1; i += 16) {
        float v = as2[csr[i]] + adn;
        v = (v >= 0.f) ? v : NEG_SLOPE * v;
        float p = __expf(v - m);
        d += p;
        pe2[i] = p;
    }
#pragma unroll
    for (int off = 8; off >= 1; off >>= 1) d += __shfl_xor(d, off, 16);
    if (l == 0) rden2[n] = 1.f / (d + 1e-16f);
}

// ---------------------------------------------------------------------------
// Layer 2 gather + bias + log_softmax. 16 lanes per node (lane = class).
// ---------------------------------------------------------------------------
__global__ __launch_bounds__(256)
void gather2(const int* __restrict__ offs, const int* __restrict__ csr,
             const float* __restrict__ pe2, const float* __restrict__ rden2,
             const float* __restrict__ z, const float* __restrict__ b2,
             float* __restrict__ out, int N) {
    int g = threadIdx.x >> 4;
    int l = threadIdx.x & 15;
    int n = blockIdx.x * 16 + g;
    if (n >= N) return;
    int s0 = offs[n], s1 = offs[n + 1];

    float acc = 0.f;
    int i = s0;
    for (; i + 4 <= s1; i += 4) {
        int sa = csr[i], sb = csr[i + 1], sc = csr[i + 2], sd = csr[i + 3];
        float pa = pe2[i], pb = pe2[i + 1], pc = pe2[i + 2], pd = pe2[i + 3];
        float za = z[sa * NCLS + l];
        float zb = z[sb * NCLS + l];
        float zc = z[sc * NCLS + l];
        float zd = z[sd * NCLS + l];
        acc = fmaf(za, pa, acc);
        acc = fmaf(zb, pb, acc);
        acc = fmaf(zc, pc, acc);
        acc = fmaf(zd, pd, acc);
    }
    for (; i < s1; ++i) acc = fmaf(z[csr[i] * NCLS + l], pe2[i], acc);

    float o = acc * rden2[n] + b2[l];

    float mx = o;
#pragma unroll
    for (int off = 8; off >= 1; off >>= 1) mx = fmaxf(mx, __shfl_xor(mx, off, 16));
    float ex = __expf(o - mx);
    float sum = ex;
#pragma unroll
    for (int off = 8; off >= 1; off >>= 1) sum += __shfl_xor(sum, off, 16);
    out[(long)n * NCLS + l] = o - mx - __logf(sum);
}

// ---------------------------------------------------------------------------
extern "C" void kernel_launch(void* const* d_in, const int* in_sizes, int n_in,
                              void* d_out, int out_size, void* d_ws, size_t ws_size,
                              hipStream_t stream) {
    const float* x        = (const float*)d_in[0];
    const int*   ei       = (const int*)  d_in[1];
    // d_in[2] = edge_attr (unused by reference)
    const float* W1       = (const float*)d_in[3];
    const float* att_src1 = (const float*)d_in[4];
    const float* att_dst1 = (const float*)d_in[5];
    const float* b1       = (const float*)d_in[6];
    const float* W2       = (const float*)d_in[7];
    const float* att_src2 = (const float*)d_in[8];
    const float* att_dst2 = (const float*)d_in[9];
    const float* b2       = (const float*)d_in[10];
    float* out = (float*)d_out;

    const int N = in_sizes[0] / FIN;        // 50000
    const int E = in_sizes[1] / 2;          // 800000
    const int Etot = E + N;                 // self-loops appended
    const int nb = (N + SCB - 1) / SCB;     // scan blocks (196)

    // Workspace layout (bytes), with aliasing for layer-2 temporaries
    char* ws = (char*)d_ws;
    size_t off = 0;
    auto alloc = [&](size_t bytes) { char* p = ws + off; off += (bytes + 255) & ~(size_t)255; return p; };
    int*    cnt    = (int*)   alloc((size_t)N * 4);
    int*    offs   = (int*)   alloc((size_t)(N + 1) * 4);
    int*    cursor = (int*)   alloc((size_t)N * 4);
    int*    csr    = (int*)   alloc((size_t)Etot * 4);
    int*    bsum   = (int*)   alloc((size_t)nb * 4);
    int*    bbase  = (int*)   alloc((size_t)nb * 4);
    float*  h1     = (float*) alloc((size_t)N * HC1 * 4);   // layer2: z aliases h1
    float*  h2     = (float*) alloc((size_t)N * HC1 * 4);
    float2* pe     = (float2*)alloc((size_t)Etot * 8);      // layer2: pe2 aliases pe
    float2* rden   = (float2*)alloc((size_t)N * 8);         // layer2: rden2 aliases
    float*  as1    = (float*) alloc((size_t)N * 2 * 4);     // layer2: as2 aliases
    float*  ad1    = (float*) alloc((size_t)N * 2 * 4);     // layer2: ad2 aliases
    (void)ws_size;

    float* z     = h1;            // safe: gather1 (reads h1) precedes gemm2 (writes z)
    float* pe2   = (float*)pe;    // safe: gather1 (reads pe) precedes scores2
    float* rden2 = (float*)rden;
    float* as2   = as1;
    float* ad2   = ad1;

    hipMemsetAsync(cnt, 0, (size_t)N * 4, stream);

    int tb = 256;
    int eb = (Etot + tb - 1) / tb;
    hist_kernel<<<eb, tb, 0, stream>>>(ei, cnt, E, N);
    scan_partial<<<nb, SCB, 0, stream>>>(cnt, bsum, N);
    scan_top<<<1, SCB, 0, stream>>>(bsum, bbase, nb);
    scan_bottom<<<nb, SCB, 0, stream>>>(cnt, bbase, offs, cursor, N);
    scatter_kernel<<<eb, tb, 0, stream>>>(ei, cursor, csr, E, N);

    gemm1_alpha<<<(N + NPB1 - 1) / NPB1, 128, 0, stream>>>(
        x, W1, att_src1, att_dst1, h1, as1, ad1, N);
    scores1<<<(N + 15) / 16, 256, 0, stream>>>(offs, csr, as1, ad1, pe, rden, N);
    gather1<<<(N + 7) / 8, 256, 0, stream>>>(offs, csr, pe, rden, h1, b1, h2, N);

    gemm2_alpha<<<(N + 15) / 16, 256, 0, stream>>>(
        h2, W2, att_src2, att_dst2, z, as2, ad2, N);
    scores2<<<(N + 15) / 16, 256, 0, stream>>>(offs, csr, as2, ad2, pe2, rden2, N);
    gather2<<<(N + 15) / 16, 256, 0, stream>>>(offs, csr, pe2, rden2, z, b2, out, N);
}

// Round 5
// 236.676 us; speedup vs baseline: 1.9972x; 1.1386x over previous
//
#include <hip/hip_runtime.h>
#include <math.h>

// Problem constants (match reference)
#define FIN   128
#define HC1   128   // H*C for layer 1
#define NCLS  16
#define NEG_SLOPE 0.2f

typedef __attribute__((ext_vector_type(8))) short bf16x8;
typedef __attribute__((ext_vector_type(4))) float f32x4;

__device__ __forceinline__ unsigned short f2bf_rne(float f) {
    unsigned int u = __float_as_uint(f);
    unsigned int r = u + 0x7FFFu + ((u >> 16) & 1u);
    return (unsigned short)(r >> 16);
}
__device__ __forceinline__ float bf2f(unsigned short h) {
    return __uint_as_float(((unsigned int)h) << 16);
}

// ---------------------------------------------------------------------------
// CSR build kernels (dst -> incoming edge list), shared by both layers
// ---------------------------------------------------------------------------
__global__ void hist_kernel(const int* __restrict__ ei, int* __restrict__ cnt,
                            int E, int N) {
    int e = blockIdx.x * blockDim.x + threadIdx.x;
    int tot = E + N;
    if (e >= tot) return;
    int d = (e < E) ? ei[E + e] : (e - E);   // self-loop dst = node id
    atomicAdd(&cnt[d], 1);
}

// ---- 3-phase device-wide exclusive scan over cnt[N] -> offs/cursor ----
#define SCB 256   // scan block size == elements per block

__global__ __launch_bounds__(SCB)
void scan_partial(const int* __restrict__ cnt, int* __restrict__ bsum, int N) {
    __shared__ int lds[SCB];
    int b = blockIdx.x, t = threadIdx.x;
    int i = b * SCB + t;
    int v = (i < N) ? cnt[i] : 0;
    lds[t] = v;
    __syncthreads();
    for (int off = SCB / 2; off >= 1; off >>= 1) {
        if (t < off) lds[t] += lds[t + off];
        __syncthreads();
    }
    if (t == 0) bsum[b] = lds[0];
}

__global__ __launch_bounds__(SCB)
void scan_top(int* __restrict__ bsum, int* __restrict__ base, int nb) {
    __shared__ int lds[SCB];
    int t = threadIdx.x;
    int v = (t < nb) ? bsum[t] : 0;
    lds[t] = v;
    __syncthreads();
    for (int off = 1; off < SCB; off <<= 1) {
        int u = (t >= off) ? lds[t - off] : 0;
        __syncthreads();
        lds[t] += u;
        __syncthreads();
    }
    if (t < nb) base[t] = lds[t] - v;   // exclusive
}

__global__ __launch_bounds__(SCB)
void scan_bottom(const int* __restrict__ cnt, const int* __restrict__ base,
                 int* __restrict__ offs, int* __restrict__ cursor, int N) {
    __shared__ int lds[SCB];
    int b = blockIdx.x, t = threadIdx.x;
    int i = b * SCB + t;
    int v = (i < N) ? cnt[i] : 0;
    lds[t] = v;
    __syncthreads();
    for (int off = 1; off < SCB; off <<= 1) {
        int u = (t >= off) ? lds[t - off] : 0;
        __syncthreads();
        lds[t] += u;
        __syncthreads();
    }
    int excl = base[b] + lds[t] - v;
    if (i < N) { offs[i] = excl; cursor[i] = excl; }
    if (i == N - 1) offs[N] = excl + v;
}

__global__ void scatter_kernel(const int* __restrict__ ei, int* __restrict__ cursor,
                               int* __restrict__ csr_src, int E, int N) {
    int e = blockIdx.x * blockDim.x + threadIdx.x;
    int tot = E + N;
    if (e >= tot) return;
    int d, s;
    if (e < E) { d = ei[E + e]; s = ei[e]; }
    else       { d = e - E;     s = e - E; }
    int pos = atomicAdd(&cursor[d], 1);
    csr_src[pos] = s;
}

// ---------------------------------------------------------------------------
// Layer 1 GEMM via split-bf16 MFMA: h1 = x @ W1, ~fp32 accuracy.
// x = xhi + xlo, W = Whi + Wlo (bf16 RNE splits);
// h = Ahi*Bhi + Ahi*Blo + Alo*Bhi   (lo*lo term ~1e-7, skipped)
// Block 256 = 4 waves; each wave: 16 rows x all 128 cols (8 MFMA tiles).
// W staged per block into LDS pre-arranged in fragment order (hi/lo),
// so B-frag load = one conflict-free ds_read_b128 per tile per k-step.
// A-frags loaded straight from global x (each row read exactly once).
// Fused alpha_src/alpha_dst per (node, head) via width-16 shfl reduce.
// C/D layout (verified m89): D row (arg0 idx) = (lane>>4)*4+reg,
// D col (arg1 idx) = lane&15. Frag k-map (g*8+j) identical for A and B
// so any hardware k-permutation cancels.
// ---------------------------------------------------------------------------
__global__ __launch_bounds__(256)
void gemm1_mfma(const float* __restrict__ x, const float* __restrict__ W,
                const float* __restrict__ a_src, const float* __restrict__ a_dst,
                float* __restrict__ h1, float* __restrict__ as1, float* __restrict__ ad1,
                int N) {
    __shared__ unsigned short whi[FIN * HC1];   // 32 KB, fragment-ordered
    __shared__ unsigned short wlo[FIN * HC1];   // 32 KB
    int tid = threadIdx.x;

    // Stage W -> LDS as bf16 hi/lo in fragment order.
    // frag offset for (k,c): kb=k>>5, g=(k&31)>>3, j=k&7, ct=c>>4, li=c&15
    //   off = ((kb*8+ct)*64 + g*16+li)*8 + j
#pragma unroll
    for (int i = 0; i < 64; ++i) {
        int idx = tid + i * 256;            // 0..16383, coalesced
        int k = idx >> 7, c = idx & 127;
        float v = W[idx];
        unsigned short hb = f2bf_rne(v);
        unsigned short lb = f2bf_rne(v - bf2f(hb));
        int kb = k >> 5, kk = k & 31;
        int g = kk >> 3, j = kk & 7;
        int ct = c >> 4, li = c & 15;
        int off = ((kb * 8 + ct) * 64 + g * 16 + li) * 8 + j;
        whi[off] = hb;
        wlo[off] = lb;
    }

    int wid = tid >> 6, lane = tid & 63;
    int li = lane & 15, g = lane >> 4;
    int rowbase = blockIdx.x * 64 + wid * 16;

    // A-frags from global: lane holds row (li), k = kb*32 + g*8 + j
    int arow = rowbase + li;
    if (arow >= N) arow = N - 1;            // clamp; invalid rows never stored
    const float* xp = x + (long)arow * FIN + g * 8;
    bf16x8 Ahi[4], Alo[4];
#pragma unroll
    for (int kb = 0; kb < 4; ++kb) {
        float4 v0 = *reinterpret_cast<const float4*>(xp + kb * 32);
        float4 v1 = *reinterpret_cast<const float4*>(xp + kb * 32 + 4);
        float vs0 = v0.x, vs1 = v0.y, vs2 = v0.z, vs3 = v0.w;
        float vs4 = v1.x, vs5 = v1.y, vs6 = v1.z, vs7 = v1.w;
        bf16x8 h8, l8;
        unsigned short hb;
        hb = f2bf_rne(vs0); h8[0] = (short)hb; l8[0] = (short)f2bf_rne(vs0 - bf2f(hb));
        hb = f2bf_rne(vs1); h8[1] = (short)hb; l8[1] = (short)f2bf_rne(vs1 - bf2f(hb));
        hb = f2bf_rne(vs2); h8[2] = (short)hb; l8[2] = (short)f2bf_rne(vs2 - bf2f(hb));
        hb = f2bf_rne(vs3); h8[3] = (short)hb; l8[3] = (short)f2bf_rne(vs3 - bf2f(hb));
        hb = f2bf_rne(vs4); h8[4] = (short)hb; l8[4] = (short)f2bf_rne(vs4 - bf2f(hb));
        hb = f2bf_rne(vs5); h8[5] = (short)hb; l8[5] = (short)f2bf_rne(vs5 - bf2f(hb));
        hb = f2bf_rne(vs6); h8[6] = (short)hb; l8[6] = (short)f2bf_rne(vs6 - bf2f(hb));
        hb = f2bf_rne(vs7); h8[7] = (short)hb; l8[7] = (short)f2bf_rne(vs7 - bf2f(hb));
        Ahi[kb] = h8; Alo[kb] = l8;
    }

    // alpha weights for this lane's column (c = ct*16 + li)
    float asr[8], adr[8];
#pragma unroll
    for (int ct = 0; ct < 8; ++ct) {
        asr[ct] = a_src[ct * 16 + li];
        adr[ct] = a_dst[ct * 16 + li];
    }

    __syncthreads();

    f32x4 acc[8];
#pragma unroll
    for (int ct = 0; ct < 8; ++ct) acc[ct] = (f32x4){0.f, 0.f, 0.f, 0.f};

#pragma unroll
    for (int kb = 0; kb < 4; ++kb) {
#pragma unroll
        for (int ct = 0; ct < 8; ++ct) {
            bf16x8 bh = *reinterpret_cast<const bf16x8*>(&whi[((kb * 8 + ct) * 64 + lane) * 8]);
            bf16x8 bl = *reinterpret_cast<const bf16x8*>(&wlo[((kb * 8 + ct) * 64 + lane) * 8]);
            acc[ct] = __builtin_amdgcn_mfma_f32_16x16x32_bf16(Alo[kb], bh, acc[ct], 0, 0, 0);
            acc[ct] = __builtin_amdgcn_mfma_f32_16x16x32_bf16(Ahi[kb], bl, acc[ct], 0, 0, 0);
            acc[ct] = __builtin_amdgcn_mfma_f32_16x16x32_bf16(Ahi[kb], bh, acc[ct], 0, 0, 0);
        }
    }

    // Epilogue: store h1 + fused per-head alpha reductions.
#pragma unroll
    for (int q = 0; q < 4; ++q) {
        int n = rowbase + g * 4 + q;
        bool valid = (n < N);
        float p0s = 0.f, p1s = 0.f, p0d = 0.f, p1d = 0.f;
#pragma unroll
        for (int ct = 0; ct < 8; ++ct) {
            float h = acc[ct][q];
            if (valid) h1[(long)n * HC1 + ct * 16 + li] = h;
            if (ct < 4) { p0s = fmaf(h, asr[ct], p0s); p0d = fmaf(h, adr[ct], p0d); }
            else        { p1s = fmaf(h, asr[ct], p1s); p1d = fmaf(h, adr[ct], p1d); }
        }
#pragma unroll
        for (int off = 8; off >= 1; off >>= 1) {
            p0s += __shfl_xor(p0s, off, 16);
            p1s += __shfl_xor(p1s, off, 16);
            p0d += __shfl_xor(p0d, off, 16);
            p1d += __shfl_xor(p1d, off, 16);
        }
        if (valid && li == 0) {
            as1[n * 2 + 0] = p0s; as1[n * 2 + 1] = p1s;
            ad1[n * 2 + 0] = p0d; ad1[n * 2 + 1] = p1d;
        }
    }
}

// ---------------------------------------------------------------------------
// Layer 1 scores: 16 lanes per node, no barriers/atomics.
// ---------------------------------------------------------------------------
__global__ __launch_bounds__(256)
void scores1(const int* __restrict__ offs, const int* __restrict__ csr,
             const float* __restrict__ as_arr, const float* __restrict__ ad_arr,
             float2* __restrict__ pe, float2* __restrict__ rden, int N) {
    int n = (blockIdx.x * blockDim.x + threadIdx.x) >> 4;
    int l = threadIdx.x & 15;
    if (n >= N) return;
    int s0 = offs[n], s1 = offs[n + 1];
    float ad0 = ad_arr[2 * n], ad1v = ad_arr[2 * n + 1];

    float m0 = -1e30f, m1 = -1e30f;
    for (int i = s0 + l; i < s1; i += 16) {
        int s = csr[i];
        float2 a = *reinterpret_cast<const float2*>(&as_arr[2 * s]);
        float v0 = a.x + ad0; v0 = (v0 >= 0.f) ? v0 : NEG_SLOPE * v0;
        float v1 = a.y + ad1v; v1 = (v1 >= 0.f) ? v1 : NEG_SLOPE * v1;
        m0 = fmaxf(m0, v0); m1 = fmaxf(m1, v1);
    }
#pragma unroll
    for (int off = 8; off >= 1; off >>= 1) {
        m0 = fmaxf(m0, __shfl_xor(m0, off, 16));
        m1 = fmaxf(m1, __shfl_xor(m1, off, 16));
    }
    float d0 = 0.f, d1 = 0.f;
    for (int i = s0 + l; i < s1; i += 16) {
        int s = csr[i];
        float2 a = *reinterpret_cast<const float2*>(&as_arr[2 * s]);
        float v0 = a.x + ad0; v0 = (v0 >= 0.f) ? v0 : NEG_SLOPE * v0;
        float v1 = a.y + ad1v; v1 = (v1 >= 0.f) ? v1 : NEG_SLOPE * v1;
        float p0 = __expf(v0 - m0), p1 = __expf(v1 - m1);
        d0 += p0; d1 += p1;
        pe[i] = make_float2(p0, p1);
    }
#pragma unroll
    for (int off = 8; off >= 1; off >>= 1) {
        d0 += __shfl_xor(d0, off, 16);
        d1 += __shfl_xor(d1, off, 16);
    }
    if (l == 0) rden[n] = make_float2(1.f / (d0 + 1e-16f), 1.f / (d1 + 1e-16f));
}

// ---------------------------------------------------------------------------
// Layer 1 gather: pure SpMM, 32 lanes x float4 per node, 8 nodes/block,
// unrolled x4, zero barriers. Fused *rden + b1 + ELU epilogue.
// ---------------------------------------------------------------------------
__global__ __launch_bounds__(256)
void gather1(const int* __restrict__ offs, const int* __restrict__ csr,
             const float2* __restrict__ pe, const float2* __restrict__ rden,
             const float* __restrict__ h1, const float* __restrict__ b1,
             float* __restrict__ h2, int N) {
    int g = threadIdx.x >> 5;        // 0..7 node-group in block
    int l = threadIdx.x & 31;        // lane in group: cols 4l..4l+3
    int n = blockIdx.x * 8 + g;
    if (n >= N) return;
    int head = l >> 4;
    int s0 = offs[n], s1 = offs[n + 1];

    float4 acc = make_float4(0.f, 0.f, 0.f, 0.f);
    int i = s0;
    for (; i + 4 <= s1; i += 4) {
        int sa = csr[i], sb = csr[i + 1], sc = csr[i + 2], sd = csr[i + 3];
        float2 pa = pe[i], pb = pe[i + 1], pc = pe[i + 2], pd = pe[i + 3];
        float4 ha = *reinterpret_cast<const float4*>(&h1[((long)sa << 7) + 4 * l]);
        float4 hb = *reinterpret_cast<const float4*>(&h1[((long)sb << 7) + 4 * l]);
        float4 hc = *reinterpret_cast<const float4*>(&h1[((long)sc << 7) + 4 * l]);
        float4 hd = *reinterpret_cast<const float4*>(&h1[((long)sd << 7) + 4 * l]);
        float wa = head ? pa.y : pa.x;
        float wb = head ? pb.y : pb.x;
        float wc = head ? pc.y : pc.x;
        float wd = head ? pd.y : pd.x;
        acc.x = fmaf(ha.x, wa, acc.x); acc.y = fmaf(ha.y, wa, acc.y);
        acc.z = fmaf(ha.z, wa, acc.z); acc.w = fmaf(ha.w, wa, acc.w);
        acc.x = fmaf(hb.x, wb, acc.x); acc.y = fmaf(hb.y, wb, acc.y);
        acc.z = fmaf(hb.z, wb, acc.z); acc.w = fmaf(hb.w, wb, acc.w);
        acc.x = fmaf(hc.x, wc, acc.x); acc.y = fmaf(hc.y, wc, acc.y);
        acc.z = fmaf(hc.z, wc, acc.z); acc.w = fmaf(hc.w, wc, acc.w);
        acc.x = fmaf(hd.x, wd, acc.x); acc.y = fmaf(hd.y, wd, acc.y);
        acc.z = fmaf(hd.z, wd, acc.z); acc.w = fmaf(hd.w, wd, acc.w);
    }
    for (; i < s1; ++i) {
        int s = csr[i];
        float2 p2 = pe[i];
        float w = head ? p2.y : p2.x;
        float4 hv = *reinterpret_cast<const float4*>(&h1[((long)s << 7) + 4 * l]);
        acc.x = fmaf(hv.x, w, acc.x); acc.y = fmaf(hv.y, w, acc.y);
        acc.z = fmaf(hv.z, w, acc.z); acc.w = fmaf(hv.w, w, acc.w);
    }
    float2 rd = rden[n];
    float r = head ? rd.y : rd.x;
    int col = 4 * l;
    float4 bb = *reinterpret_cast<const float4*>(&b1[col]);
    float4 o;
    o.x = acc.x * r + bb.x; o.y = acc.y * r + bb.y;
    o.z = acc.z * r + bb.z; o.w = acc.w * r + bb.w;
    o.x = (o.x > 0.f) ? o.x : expm1f(o.x);
    o.y = (o.y > 0.f) ? o.y : expm1f(o.y);
    o.z = (o.z > 0.f) ? o.z : expm1f(o.z);
    o.w = (o.w > 0.f) ? o.w : expm1f(o.w);
    *reinterpret_cast<float4*>(&h2[((long)n << 7) + col]) = o;
}

// ---------------------------------------------------------------------------
// Layer 2 GEMM
// ---------------------------------------------------------------------------
__global__ __launch_bounds__(256)
void gemm2_alpha(const float* __restrict__ h2, const float* __restrict__ W2,
                 const float* __restrict__ a_src, const float* __restrict__ a_dst,
                 float* __restrict__ z, float* __restrict__ as2, float* __restrict__ ad2,
                 int N) {
    __shared__ float hs[16][FIN + 4];
    __shared__ float ws[FIN * NCLS];
    int tid = threadIdx.x;
    int n0 = blockIdx.x * 16;
    for (int i = tid; i < FIN * NCLS; i += 256) ws[i] = W2[i];
    for (int i = tid; i < 16 * FIN; i += 256) {
        int r = i >> 7, c = i & 127;
        int n = n0 + r;
        hs[r][c] = (n < N) ? h2[(long)n * FIN + c] : 0.f;
    }
    __syncthreads();

    int r = tid >> 4, c = tid & 15;
    int n = n0 + r;
    float acc = 0.f;
#pragma unroll 4
    for (int k = 0; k < FIN; ++k)
        acc = fmaf(hs[r][k], ws[k * NCLS + c], acc);

    float sa = acc * a_src[c];
    float da = acc * a_dst[c];
    for (int off = 8; off >= 1; off >>= 1) {
        sa += __shfl_xor(sa, off, 16);
        da += __shfl_xor(da, off, 16);
    }
    if (n < N) {
        z[n * NCLS + c] = acc;
        if (c == 0) { as2[n] = sa; ad2[n] = da; }
    }
}

// ---------------------------------------------------------------------------
// Layer 2 scores (H=1): 16 lanes per node.
// ---------------------------------------------------------------------------
__global__ __launch_bounds__(256)
void scores2(const int* __restrict__ offs, const int* __restrict__ csr,
             const float* __restrict__ as2, const float* __restrict__ ad2,
             float* __restrict__ pe2, float* __restrict__ rden2, int N) {
    int n = (blockIdx.x * blockDim.x + threadIdx.x) >> 4;
    int l = threadIdx.x & 15;
    if (n >= N) return;
    int s0 = offs[n], s1 = offs[n + 1];
    float adn = ad2[n];

    float m = -1e30f;
    for (int i = s0 + l; i < s1; i += 16) {
        float v = as2[csr[i]] + adn;
        v = (v >= 0.f) ? v : NEG_SLOPE * v;
        m = fmaxf(m, v);
    }
#pragma unroll
    for (int off = 8; off >= 1; off >>= 1) m = fmaxf(m, __shfl_xor(m, off, 16));
    float d = 0.f;
    for (int i = s0 + l; i < s1; i += 16) {
        float v = as2[csr[i]] + adn;
        v = (v >= 0.f) ? v : NEG_SLOPE * v;
        float p = __expf(v - m);
        d += p;
        pe2[i] = p;
    }
#pragma unroll
    for (int off = 8; off >= 1; off >>= 1) d += __shfl_xor(d, off, 16);
    if (l == 0) rden2[n] = 1.f / (d + 1e-16f);
}

// ---------------------------------------------------------------------------
// Layer 2 gather + bias + log_softmax. 16 lanes per node (lane = class).
// ---------------------------------------------------------------------------
__global__ __launch_bounds__(256)
void gather2(const int* __restrict__ offs, const int* __restrict__ csr,
             const float* __restrict__ pe2, const float* __restrict__ rden2,
             const float* __restrict__ z, const float* __restrict__ b2,
             float* __restrict__ out, int N) {
    int g = threadIdx.x >> 4;
    int l = threadIdx.x & 15;
    int n = blockIdx.x * 16 + g;
    if (n >= N) return;
    int s0 = offs[n], s1 = offs[n + 1];

    float acc = 0.f;
    int i = s0;
    for (; i + 4 <= s1; i += 4) {
        int sa = csr[i], sb = csr[i + 1], sc = csr[i + 2], sd = csr[i + 3];
        float pa = pe2[i], pb = pe2[i + 1], pc = pe2[i + 2], pd = pe2[i + 3];
        float za = z[sa * NCLS + l];
        float zb = z[sb * NCLS + l];
        float zc = z[sc * NCLS + l];
        float zd = z[sd * NCLS + l];
        acc = fmaf(za, pa, acc);
        acc = fmaf(zb, pb, acc);
        acc = fmaf(zc, pc, acc);
        acc = fmaf(zd, pd, acc);
    }
    for (; i < s1; ++i) acc = fmaf(z[csr[i] * NCLS + l], pe2[i], acc);

    float o = acc * rden2[n] + b2[l];

    float mx = o;
#pragma unroll
    for (int off = 8; off >= 1; off >>= 1) mx = fmaxf(mx, __shfl_xor(mx, off, 16));
    float ex = __expf(o - mx);
    float sum = ex;
#pragma unroll
    for (int off = 8; off >= 1; off >>= 1) sum += __shfl_xor(sum, off, 16);
    out[(long)n * NCLS + l] = o - mx - __logf(sum);
}

// ---------------------------------------------------------------------------
extern "C" void kernel_launch(void* const* d_in, const int* in_sizes, int n_in,
                              void* d_out, int out_size, void* d_ws, size_t ws_size,
                              hipStream_t stream) {
    const float* x        = (const float*)d_in[0];
    const int*   ei       = (const int*)  d_in[1];
    // d_in[2] = edge_attr (unused by reference)
    const float* W1       = (const float*)d_in[3];
    const float* att_src1 = (const float*)d_in[4];
    const float* att_dst1 = (const float*)d_in[5];
    const float* b1       = (const float*)d_in[6];
    const float* W2       = (const float*)d_in[7];
    const float* att_src2 = (const float*)d_in[8];
    const float* att_dst2 = (const float*)d_in[9];
    const float* b2       = (const float*)d_in[10];
    float* out = (float*)d_out;

    const int N = in_sizes[0] / FIN;        // 50000
    const int E = in_sizes[1] / 2;          // 800000
    const int Etot = E + N;                 // self-loops appended
    const int nb = (N + SCB - 1) / SCB;     // scan blocks (196)

    // Workspace layout (bytes), with aliasing for layer-2 temporaries
    char* ws = (char*)d_ws;
    size_t off = 0;
    auto alloc = [&](size_t bytes) { char* p = ws + off; off += (bytes + 255) & ~(size_t)255; return p; };
    int*    cnt    = (int*)   alloc((size_t)N * 4);
    int*    offs   = (int*)   alloc((size_t)(N + 1) * 4);
    int*    cursor = (int*)   alloc((size_t)N * 4);
    int*    csr    = (int*)   alloc((size_t)Etot * 4);
    int*    bsum   = (int*)   alloc((size_t)nb * 4);
    int*    bbase  = (int*)   alloc((size_t)nb * 4);
    float*  h1     = (float*) alloc((size_t)N * HC1 * 4);   // layer2: z aliases h1
    float*  h2     = (float*) alloc((size_t)N * HC1 * 4);
    float2* pe     = (float2*)alloc((size_t)Etot * 8);      // layer2: pe2 aliases pe
    float2* rden   = (float2*)alloc((size_t)N * 8);         // layer2: rden2 aliases
    float*  as1    = (float*) alloc((size_t)N * 2 * 4);     // layer2: as2 aliases
    float*  ad1    = (float*) alloc((size_t)N * 2 * 4);     // layer2: ad2 aliases
    (void)ws_size;

    float* z     = h1;            // safe: gather1 (reads h1) precedes gemm2 (writes z)
    float* pe2   = (float*)pe;    // safe: gather1 (reads pe) precedes scores2
    float* rden2 = (float*)rden;
    float* as2   = as1;
    float* ad2   = ad1;

    hipMemsetAsync(cnt, 0, (size_t)N * 4, stream);

    int tb = 256;
    int eb = (Etot + tb - 1) / tb;
    hist_kernel<<<eb, tb, 0, stream>>>(ei, cnt, E, N);
    scan_partial<<<nb, SCB, 0, stream>>>(cnt, bsum, N);
    scan_top<<<1, SCB, 0, stream>>>(bsum, bbase, nb);
    scan_bottom<<<nb, SCB, 0, stream>>>(cnt, bbase, offs, cursor, N);
    scatter_kernel<<<eb, tb, 0, stream>>>(ei, cursor, csr, E, N);

    gemm1_mfma<<<(N + 63) / 64, 256, 0, stream>>>(
        x, W1, att_src1, att_dst1, h1, as1, ad1, N);
    scores1<<<(N + 15) / 16, 256, 0, stream>>>(offs, csr, as1, ad1, pe, rden, N);
    gather1<<<(N + 7) / 8, 256, 0, stream>>>(offs, csr, pe, rden, h1, b1, h2, N);

    gemm2_alpha<<<(N + 15) / 16, 256, 0, stream>>>(
        h2, W2, att_src2, att_dst2, z, as2, ad2, N);
    scores2<<<(N + 15) / 16, 256, 0, stream>>>(offs, csr, as2, ad2, pe2, rden2, N);
    gather2<<<(N + 15) / 16, 256, 0, stream>>>(offs, csr, pe2, rden2, z, b2, out, N);
}

// Round 6
// 214.533 us; speedup vs baseline: 2.2034x; 1.1032x over previous
//
#include <hip/hip_runtime.h>
#include <math.h>

// Problem constants (match reference)
#define FIN   128
#define HC1   128   // H*C for layer 1
#define NCLS  16
#define NEG_SLOPE 0.2f

typedef __attribute__((ext_vector_type(8))) short bf16x8;
typedef __attribute__((ext_vector_type(4))) float f32x4;

__device__ __forceinline__ unsigned short f2bf_rne(float f) {
    unsigned int u = __float_as_uint(f);
    unsigned int r = u + 0x7FFFu + ((u >> 16) & 1u);
    return (unsigned short)(r >> 16);
}
__device__ __forceinline__ float bf2f(unsigned short h) {
    return __uint_as_float(((unsigned int)h) << 16);
}
// unpack a uint holding two bf16: lo = element 0, hi = element 1
__device__ __forceinline__ float bflo(unsigned int u) { return __uint_as_float(u << 16); }
__device__ __forceinline__ float bfhi(unsigned int u) { return __uint_as_float(u & 0xFFFF0000u); }

// ---------------------------------------------------------------------------
// CSR build kernels (dst -> incoming edge list), shared by both layers
// ---------------------------------------------------------------------------
__global__ void hist_kernel(const int* __restrict__ ei, int* __restrict__ cnt,
                            int E, int N) {
    int e = blockIdx.x * blockDim.x + threadIdx.x;
    int tot = E + N;
    if (e >= tot) return;
    int d = (e < E) ? ei[E + e] : (e - E);   // self-loop dst = node id
    atomicAdd(&cnt[d], 1);
}

// ---- 3-phase device-wide exclusive scan over cnt[N] -> offs/cursor ----
#define SCB 256   // scan block size == elements per block

__global__ __launch_bounds__(SCB)
void scan_partial(const int* __restrict__ cnt, int* __restrict__ bsum, int N) {
    __shared__ int lds[SCB];
    int b = blockIdx.x, t = threadIdx.x;
    int i = b * SCB + t;
    int v = (i < N) ? cnt[i] : 0;
    lds[t] = v;
    __syncthreads();
    for (int off = SCB / 2; off >= 1; off >>= 1) {
        if (t < off) lds[t] += lds[t + off];
        __syncthreads();
    }
    if (t == 0) bsum[b] = lds[0];
}

__global__ __launch_bounds__(SCB)
void scan_top(int* __restrict__ bsum, int* __restrict__ base, int nb) {
    __shared__ int lds[SCB];
    int t = threadIdx.x;
    int v = (t < nb) ? bsum[t] : 0;
    lds[t] = v;
    __syncthreads();
    for (int off = 1; off < SCB; off <<= 1) {
        int u = (t >= off) ? lds[t - off] : 0;
        __syncthreads();
        lds[t] += u;
        __syncthreads();
    }
    if (t < nb) base[t] = lds[t] - v;   // exclusive
}

__global__ __launch_bounds__(SCB)
void scan_bottom(const int* __restrict__ cnt, const int* __restrict__ base,
                 int* __restrict__ offs, int* __restrict__ cursor, int N) {
    __shared__ int lds[SCB];
    int b = blockIdx.x, t = threadIdx.x;
    int i = b * SCB + t;
    int v = (i < N) ? cnt[i] : 0;
    lds[t] = v;
    __syncthreads();
    for (int off = 1; off < SCB; off <<= 1) {
        int u = (t >= off) ? lds[t - off] : 0;
        __syncthreads();
        lds[t] += u;
        __syncthreads();
    }
    int excl = base[b] + lds[t] - v;
    if (i < N) { offs[i] = excl; cursor[i] = excl; }
    if (i == N - 1) offs[N] = excl + v;
}

__global__ void scatter_kernel(const int* __restrict__ ei, int* __restrict__ cursor,
                               int* __restrict__ csr_src, int E, int N) {
    int e = blockIdx.x * blockDim.x + threadIdx.x;
    int tot = E + N;
    if (e >= tot) return;
    int d, s;
    if (e < E) { d = ei[E + e]; s = ei[e]; }
    else       { d = e - E;     s = e - E; }
    int pos = atomicAdd(&cursor[d], 1);
    csr_src[pos] = s;
}

// ---------------------------------------------------------------------------
// Layer 1 GEMM via split-bf16 MFMA: h1 = x @ W1, ~fp32 accuracy.
// h1 is stored as bf16 (halves the gather traffic downstream); alpha
// scalars are computed from the full fp32 accumulator before rounding.
// ---------------------------------------------------------------------------
__global__ __launch_bounds__(256)
void gemm1_mfma(const float* __restrict__ x, const float* __restrict__ W,
                const float* __restrict__ a_src, const float* __restrict__ a_dst,
                unsigned short* __restrict__ h1b, float* __restrict__ as1,
                float* __restrict__ ad1, int N) {
    __shared__ unsigned short whi[FIN * HC1];   // 32 KB, fragment-ordered
    __shared__ unsigned short wlo[FIN * HC1];   // 32 KB
    int tid = threadIdx.x;

    // Stage W -> LDS as bf16 hi/lo in fragment order.
#pragma unroll
    for (int i = 0; i < 64; ++i) {
        int idx = tid + i * 256;            // 0..16383, coalesced
        int k = idx >> 7, c = idx & 127;
        float v = W[idx];
        unsigned short hb = f2bf_rne(v);
        unsigned short lb = f2bf_rne(v - bf2f(hb));
        int kb = k >> 5, kk = k & 31;
        int g = kk >> 3, j = kk & 7;
        int ct = c >> 4, li = c & 15;
        int off = ((kb * 8 + ct) * 64 + g * 16 + li) * 8 + j;
        whi[off] = hb;
        wlo[off] = lb;
    }

    int wid = tid >> 6, lane = tid & 63;
    int li = lane & 15, g = lane >> 4;
    int rowbase = blockIdx.x * 64 + wid * 16;

    int arow = rowbase + li;
    if (arow >= N) arow = N - 1;            // clamp; invalid rows never stored
    const float* xp = x + (long)arow * FIN + g * 8;
    bf16x8 Ahi[4], Alo[4];
#pragma unroll
    for (int kb = 0; kb < 4; ++kb) {
        float4 v0 = *reinterpret_cast<const float4*>(xp + kb * 32);
        float4 v1 = *reinterpret_cast<const float4*>(xp + kb * 32 + 4);
        float vs0 = v0.x, vs1 = v0.y, vs2 = v0.z, vs3 = v0.w;
        float vs4 = v1.x, vs5 = v1.y, vs6 = v1.z, vs7 = v1.w;
        bf16x8 h8, l8;
        unsigned short hb;
        hb = f2bf_rne(vs0); h8[0] = (short)hb; l8[0] = (short)f2bf_rne(vs0 - bf2f(hb));
        hb = f2bf_rne(vs1); h8[1] = (short)hb; l8[1] = (short)f2bf_rne(vs1 - bf2f(hb));
        hb = f2bf_rne(vs2); h8[2] = (short)hb; l8[2] = (short)f2bf_rne(vs2 - bf2f(hb));
        hb = f2bf_rne(vs3); h8[3] = (short)hb; l8[3] = (short)f2bf_rne(vs3 - bf2f(hb));
        hb = f2bf_rne(vs4); h8[4] = (short)hb; l8[4] = (short)f2bf_rne(vs4 - bf2f(hb));
        hb = f2bf_rne(vs5); h8[5] = (short)hb; l8[5] = (short)f2bf_rne(vs5 - bf2f(hb));
        hb = f2bf_rne(vs6); h8[6] = (short)hb; l8[6] = (short)f2bf_rne(vs6 - bf2f(hb));
        hb = f2bf_rne(vs7); h8[7] = (short)hb; l8[7] = (short)f2bf_rne(vs7 - bf2f(hb));
        Ahi[kb] = h8; Alo[kb] = l8;
    }

    float asr[8], adr[8];
#pragma unroll
    for (int ct = 0; ct < 8; ++ct) {
        asr[ct] = a_src[ct * 16 + li];
        adr[ct] = a_dst[ct * 16 + li];
    }

    __syncthreads();

    f32x4 acc[8];
#pragma unroll
    for (int ct = 0; ct < 8; ++ct) acc[ct] = (f32x4){0.f, 0.f, 0.f, 0.f};

#pragma unroll
    for (int kb = 0; kb < 4; ++kb) {
#pragma unroll
        for (int ct = 0; ct < 8; ++ct) {
            bf16x8 bh = *reinterpret_cast<const bf16x8*>(&whi[((kb * 8 + ct) * 64 + lane) * 8]);
            bf16x8 bl = *reinterpret_cast<const bf16x8*>(&wlo[((kb * 8 + ct) * 64 + lane) * 8]);
            acc[ct] = __builtin_amdgcn_mfma_f32_16x16x32_bf16(Alo[kb], bh, acc[ct], 0, 0, 0);
            acc[ct] = __builtin_amdgcn_mfma_f32_16x16x32_bf16(Ahi[kb], bl, acc[ct], 0, 0, 0);
            acc[ct] = __builtin_amdgcn_mfma_f32_16x16x32_bf16(Ahi[kb], bh, acc[ct], 0, 0, 0);
        }
    }

    // Epilogue: store h1 (bf16) + fused per-head alpha reductions (fp32).
#pragma unroll
    for (int q = 0; q < 4; ++q) {
        int n = rowbase + g * 4 + q;
        bool valid = (n < N);
        float p0s = 0.f, p1s = 0.f, p0d = 0.f, p1d = 0.f;
#pragma unroll
        for (int ct = 0; ct < 8; ++ct) {
            float h = acc[ct][q];
            if (valid) h1b[(long)n * HC1 + ct * 16 + li] = f2bf_rne(h);
            if (ct < 4) { p0s = fmaf(h, asr[ct], p0s); p0d = fmaf(h, adr[ct], p0d); }
            else        { p1s = fmaf(h, asr[ct], p1s); p1d = fmaf(h, adr[ct], p1d); }
        }
#pragma unroll
        for (int off = 8; off >= 1; off >>= 1) {
            p0s += __shfl_xor(p0s, off, 16);
            p1s += __shfl_xor(p1s, off, 16);
            p0d += __shfl_xor(p0d, off, 16);
            p1d += __shfl_xor(p1d, off, 16);
        }
        if (valid && li == 0) {
            as1[n * 2 + 0] = p0s; as1[n * 2 + 1] = p1s;
            ad1[n * 2 + 0] = p0d; ad1[n * 2 + 1] = p1d;
        }
    }
}

// ---------------------------------------------------------------------------
// Layer 1 scores: 16 lanes per node, no barriers/atomics.
// ---------------------------------------------------------------------------
__global__ __launch_bounds__(256)
void scores1(const int* __restrict__ offs, const int* __restrict__ csr,
             const float* __restrict__ as_arr, const float* __restrict__ ad_arr,
             float2* __restrict__ pe, float2* __restrict__ rden, int N) {
    int n = (blockIdx.x * blockDim.x + threadIdx.x) >> 4;
    int l = threadIdx.x & 15;
    if (n >= N) return;
    int s0 = offs[n], s1 = offs[n + 1];
    float ad0 = ad_arr[2 * n], ad1v = ad_arr[2 * n + 1];

    float m0 = -1e30f, m1 = -1e30f;
    for (int i = s0 + l; i < s1; i += 16) {
        int s = csr[i];
        float2 a = *reinterpret_cast<const float2*>(&as_arr[2 * s]);
        float v0 = a.x + ad0; v0 = (v0 >= 0.f) ? v0 : NEG_SLOPE * v0;
        float v1 = a.y + ad1v; v1 = (v1 >= 0.f) ? v1 : NEG_SLOPE * v1;
        m0 = fmaxf(m0, v0); m1 = fmaxf(m1, v1);
    }
#pragma unroll
    for (int off = 8; off >= 1; off >>= 1) {
        m0 = fmaxf(m0, __shfl_xor(m0, off, 16));
        m1 = fmaxf(m1, __shfl_xor(m1, off, 16));
    }
    float d0 = 0.f, d1 = 0.f;
    for (int i = s0 + l; i < s1; i += 16) {
        int s = csr[i];
        float2 a = *reinterpret_cast<const float2*>(&as_arr[2 * s]);
        float v0 = a.x + ad0; v0 = (v0 >= 0.f) ? v0 : NEG_SLOPE * v0;
        float v1 = a.y + ad1v; v1 = (v1 >= 0.f) ? v1 : NEG_SLOPE * v1;
        float p0 = __expf(v0 - m0), p1 = __expf(v1 - m1);
        d0 += p0; d1 += p1;
        pe[i] = make_float2(p0, p1);
    }
#pragma unroll
    for (int off = 8; off >= 1; off >>= 1) {
        d0 += __shfl_xor(d0, off, 16);
        d1 += __shfl_xor(d1, off, 16);
    }
    if (l == 0) rden[n] = make_float2(1.f / (d0 + 1e-16f), 1.f / (d1 + 1e-16f));
}

// ---------------------------------------------------------------------------
// Layer 1 gather: pure SpMM over bf16 h1 rows (256 B each).
// 32 lanes x uint2 (4 bf16) per node, 8 nodes/block, unrolled x4, no barriers.
// Fused *rden + b1 + ELU epilogue; h2 stays fp32.
// ---------------------------------------------------------------------------
__global__ __launch_bounds__(256)
void gather1(const int* __restrict__ offs, const int* __restrict__ csr,
             const float2* __restrict__ pe, const float2* __restrict__ rden,
             const unsigned short* __restrict__ h1b, const float* __restrict__ b1,
             float* __restrict__ h2, int N) {
    int g = threadIdx.x >> 5;        // 0..7 node-group in block
    int l = threadIdx.x & 31;        // lane in group: cols 4l..4l+3
    int n = blockIdx.x * 8 + g;
    if (n >= N) return;
    int head = l >> 4;
    int s0 = offs[n], s1 = offs[n + 1];

    float4 acc = make_float4(0.f, 0.f, 0.f, 0.f);
    int i = s0;
    for (; i + 4 <= s1; i += 4) {
        int sa = csr[i], sb = csr[i + 1], sc = csr[i + 2], sd = csr[i + 3];
        float2 pa = pe[i], pb = pe[i + 1], pc = pe[i + 2], pd = pe[i + 3];
        uint2 ua = *reinterpret_cast<const uint2*>(&h1b[((long)sa << 7) + 4 * l]);
        uint2 ub = *reinterpret_cast<const uint2*>(&h1b[((long)sb << 7) + 4 * l]);
        uint2 uc = *reinterpret_cast<const uint2*>(&h1b[((long)sc << 7) + 4 * l]);
        uint2 ud = *reinterpret_cast<const uint2*>(&h1b[((long)sd << 7) + 4 * l]);
        float wa = head ? pa.y : pa.x;
        float wb = head ? pb.y : pb.x;
        float wc = head ? pc.y : pc.x;
        float wd = head ? pd.y : pd.x;
        acc.x = fmaf(bflo(ua.x), wa, acc.x); acc.y = fmaf(bfhi(ua.x), wa, acc.y);
        acc.z = fmaf(bflo(ua.y), wa, acc.z); acc.w = fmaf(bfhi(ua.y), wa, acc.w);
        acc.x = fmaf(bflo(ub.x), wb, acc.x); acc.y = fmaf(bfhi(ub.x), wb, acc.y);
        acc.z = fmaf(bflo(ub.y), wb, acc.z); acc.w = fmaf(bfhi(ub.y), wb, acc.w);
        acc.x = fmaf(bflo(uc.x), wc, acc.x); acc.y = fmaf(bfhi(uc.x), wc, acc.y);
        acc.z = fmaf(bflo(uc.y), wc, acc.z); acc.w = fmaf(bfhi(uc.y), wc, acc.w);
        acc.x = fmaf(bflo(ud.x), wd, acc.x); acc.y = fmaf(bfhi(ud.x), wd, acc.y);
        acc.z = fmaf(bflo(ud.y), wd, acc.z); acc.w = fmaf(bfhi(ud.y), wd, acc.w);
    }
    for (; i < s1; ++i) {
        int s = csr[i];
        float2 p2 = pe[i];
        float w = head ? p2.y : p2.x;
        uint2 u = *reinterpret_cast<const uint2*>(&h1b[((long)s << 7) + 4 * l]);
        acc.x = fmaf(bflo(u.x), w, acc.x); acc.y = fmaf(bfhi(u.x), w, acc.y);
        acc.z = fmaf(bflo(u.y), w, acc.z); acc.w = fmaf(bfhi(u.y), w, acc.w);
    }
    float2 rd = rden[n];
    float r = head ? rd.y : rd.x;
    int col = 4 * l;
    float4 bb = *reinterpret_cast<const float4*>(&b1[col]);
    float4 o;
    o.x = acc.x * r + bb.x; o.y = acc.y * r + bb.y;
    o.z = acc.z * r + bb.z; o.w = acc.w * r + bb.w;
    o.x = (o.x > 0.f) ? o.x : expm1f(o.x);
    o.y = (o.y > 0.f) ? o.y : expm1f(o.y);
    o.z = (o.z > 0.f) ? o.z : expm1f(o.z);
    o.w = (o.w > 0.f) ? o.w : expm1f(o.w);
    *reinterpret_cast<float4*>(&h2[((long)n << 7) + col]) = o;
}

// ---------------------------------------------------------------------------
// Layer 2 GEMM
// ---------------------------------------------------------------------------
__global__ __launch_bounds__(256)
void gemm2_alpha(const float* __restrict__ h2, const float* __restrict__ W2,
                 const float* __restrict__ a_src, const float* __restrict__ a_dst,
                 float* __restrict__ z, float* __restrict__ as2, float* __restrict__ ad2,
                 int N) {
    __shared__ float hs[16][FIN + 4];
    __shared__ float ws[FIN * NCLS];
    int tid = threadIdx.x;
    int n0 = blockIdx.x * 16;
    for (int i = tid; i < FIN * NCLS; i += 256) ws[i] = W2[i];
    for (int i = tid; i < 16 * FIN; i += 256) {
        int r = i >> 7, c = i & 127;
        int n = n0 + r;
        hs[r][c] = (n < N) ? h2[(long)n * FIN + c] : 0.f;
    }
    __syncthreads();

    int r = tid >> 4, c = tid & 15;
    int n = n0 + r;
    float acc = 0.f;
#pragma unroll 4
    for (int k = 0; k < FIN; ++k)
        acc = fmaf(hs[r][k], ws[k * NCLS + c], acc);

    float sa = acc * a_src[c];
    float da = acc * a_dst[c];
    for (int off = 8; off >= 1; off >>= 1) {
        sa += __shfl_xor(sa, off, 16);
        da += __shfl_xor(da, off, 16);
    }
    if (n < N) {
        z[n * NCLS + c] = acc;
        if (c == 0) { as2[n] = sa; ad2[n] = da; }
    }
}

// ---------------------------------------------------------------------------
// Layer 2 scores (H=1): 16 lanes per node.
// ---------------------------------------------------------------------------
__global__ __launch_bounds__(256)
void scores2(const int* __restrict__ offs, const int* __restrict__ csr,
             const float* __restrict__ as2, const float* __restrict__ ad2,
             float* __restrict__ pe2, float* __restrict__ rden2, int N) {
    int n = (blockIdx.x * blockDim.x + threadIdx.x) >> 4;
    int l = threadIdx.x & 15;
    if (n >= N) return;
    int s0 = offs[n], s1 = offs[n + 1];
    float adn = ad2[n];

    float m = -1e30f;
    for (int i = s0 + l; i < s1; i += 16) {
        float v = as2[csr[i]] + adn;
        v = (v >= 0.f) ? v : NEG_SLOPE * v;
        m = fmaxf(m, v);
    }
#pragma unroll
    for (int off = 8; off >= 1; off >>= 1) m = fmaxf(m, __shfl_xor(m, off, 16));
    float d = 0.f;
    for (int i = s0 + l; i < s1; i += 16) {
        float v = as2[csr[i]] + adn;
        v = (v >= 0.f) ? v : NEG_SLOPE * v;
        float p = __expf(v - m);
        d += p;
        pe2[i] = p;
    }
#pragma unroll
    for (int off = 8; off >= 1; off >>= 1) d += __shfl_xor(d, off, 16);
    if (l == 0) rden2[n] = 1.f / (d + 1e-16f);
}

// ---------------------------------------------------------------------------
// Layer 2 gather + bias + log_softmax. 16 lanes per node (lane = class).
// ---------------------------------------------------------------------------
__global__ __launch_bounds__(256)
void gather2(const int* __restrict__ offs, const int* __restrict__ csr,
             const float* __restrict__ pe2, const float* __restrict__ rden2,
             const float* __restrict__ z, const float* __restrict__ b2,
             float* __restrict__ out, int N) {
    int g = threadIdx.x >> 4;
    int l = threadIdx.x & 15;
    int n = blockIdx.x * 16 + g;
    if (n >= N) return;
    int s0 = offs[n], s1 = offs[n + 1];

    float acc = 0.f;
    int i = s0;
    for (; i + 4 <= s1; i += 4) {
        int sa = csr[i], sb = csr[i + 1], sc = csr[i + 2], sd = csr[i + 3];
        float pa = pe2[i], pb = pe2[i + 1], pc = pe2[i + 2], pd = pe2[i + 3];
        float za = z[sa * NCLS + l];
        float zb = z[sb * NCLS + l];
        float zc = z[sc * NCLS + l];
        float zd = z[sd * NCLS + l];
        acc = fmaf(za, pa, acc);
        acc = fmaf(zb, pb, acc);
        acc = fmaf(zc, pc, acc);
        acc = fmaf(zd, pd, acc);
    }
    for (; i < s1; ++i) acc = fmaf(z[csr[i] * NCLS + l], pe2[i], acc);

    float o = acc * rden2[n] + b2[l];

    float mx = o;
#pragma unroll
    for (int off = 8; off >= 1; off >>= 1) mx = fmaxf(mx, __shfl_xor(mx, off, 16));
    float ex = __expf(o - mx);
    float sum = ex;
#pragma unroll
    for (int off = 8; off >= 1; off >>= 1) sum += __shfl_xor(sum, off, 16);
    out[(long)n * NCLS + l] = o - mx - __logf(sum);
}

// ---------------------------------------------------------------------------
extern "C" void kernel_launch(void* const* d_in, const int* in_sizes, int n_in,
                              void* d_out, int out_size, void* d_ws, size_t ws_size,
                              hipStream_t stream) {
    const float* x        = (const float*)d_in[0];
    const int*   ei       = (const int*)  d_in[1];
    // d_in[2] = edge_attr (unused by reference)
    const float* W1       = (const float*)d_in[3];
    const float* att_src1 = (const float*)d_in[4];
    const float* att_dst1 = (const float*)d_in[5];
    const float* b1       = (const float*)d_in[6];
    const float* W2       = (const float*)d_in[7];
    const float* att_src2 = (const float*)d_in[8];
    const float* att_dst2 = (const float*)d_in[9];
    const float* b2       = (const float*)d_in[10];
    float* out = (float*)d_out;

    const int N = in_sizes[0] / FIN;        // 50000
    const int E = in_sizes[1] / 2;          // 800000
    const int Etot = E + N;                 // self-loops appended
    const int nb = (N + SCB - 1) / SCB;     // scan blocks (196)

    // Workspace layout (bytes), with aliasing for layer-2 temporaries
    char* ws = (char*)d_ws;
    size_t off = 0;
    auto alloc = [&](size_t bytes) { char* p = ws + off; off += (bytes + 255) & ~(size_t)255; return p; };
    int*    cnt    = (int*)   alloc((size_t)N * 4);
    int*    offs   = (int*)   alloc((size_t)(N + 1) * 4);
    int*    cursor = (int*)   alloc((size_t)N * 4);
    int*    csr    = (int*)   alloc((size_t)Etot * 4);
    int*    bsum   = (int*)   alloc((size_t)nb * 4);
    int*    bbase  = (int*)   alloc((size_t)nb * 4);
    unsigned short* h1b = (unsigned short*)alloc((size_t)N * HC1 * 2);  // bf16
    float*  h2     = (float*) alloc((size_t)N * HC1 * 4);
    float*  z      = (float*) alloc((size_t)N * NCLS * 4);
    float2* pe     = (float2*)alloc((size_t)Etot * 8);      // layer2: pe2 aliases pe
    float2* rden   = (float2*)alloc((size_t)N * 8);         // layer2: rden2 aliases
    float*  as1    = (float*) alloc((size_t)N * 2 * 4);     // layer2: as2 aliases
    float*  ad1    = (float*) alloc((size_t)N * 2 * 4);     // layer2: ad2 aliases
    (void)ws_size;

    float* pe2   = (float*)pe;    // safe: gather1 (reads pe) precedes scores2
    float* rden2 = (float*)rden;
    float* as2   = as1;
    float* ad2   = ad1;

    hipMemsetAsync(cnt, 0, (size_t)N * 4, stream);

    int tb = 256;
    int eb = (Etot + tb - 1) / tb;
    hist_kernel<<<eb, tb, 0, stream>>>(ei, cnt, E, N);
    scan_partial<<<nb, SCB, 0, stream>>>(cnt, bsum, N);
    scan_top<<<1, SCB, 0, stream>>>(bsum, bbase, nb);
    scan_bottom<<<nb, SCB, 0, stream>>>(cnt, bbase, offs, cursor, N);
    scatter_kernel<<<eb, tb, 0, stream>>>(ei, cursor, csr, E, N);

    gemm1_mfma<<<(N + 63) / 64, 256, 0, stream>>>(
        x, W1, att_src1, att_dst1, h1b, as1, ad1, N);
    scores1<<<(N + 15) / 16, 256, 0, stream>>>(offs, csr, as1, ad1, pe, rden, N);
    gather1<<<(N + 7) / 8, 256, 0, stream>>>(offs, csr, pe, rden, h1b, b1, h2, N);

    gemm2_alpha<<<(N + 15) / 16, 256, 0, stream>>>(
        h2, W2, att_src2, att_dst2, z, as2, ad2, N);
    scores2<<<(N + 15) / 16, 256, 0, stream>>>(offs, csr, as2, ad2, pe2, rden2, N);
    gather2<<<(N + 15) / 16, 256, 0, stream>>>(offs, csr, pe2, rden2, z, b2, out, N);
}

// Round 7
// 210.865 us; speedup vs baseline: 2.2417x; 1.0174x over previous
//
#include <hip/hip_runtime.h>
#include <math.h>

// Problem constants (match reference)
#define FIN   128
#define HC1   128   // H*C for layer 1
#define NCLS  16
#define NEG_SLOPE 0.2f

typedef __attribute__((ext_vector_type(8))) short bf16x8;
typedef __attribute__((ext_vector_type(4))) float f32x4;

__device__ __forceinline__ unsigned short f2bf_rne(float f) {
    unsigned int u = __float_as_uint(f);
    unsigned int r = u + 0x7FFFu + ((u >> 16) & 1u);
    return (unsigned short)(r >> 16);
}
__device__ __forceinline__ float bf2f(unsigned short h) {
    return __uint_as_float(((unsigned int)h) << 16);
}
// unpack a uint holding two bf16: lo = element 0, hi = element 1
__device__ __forceinline__ float bflo(unsigned int u) { return __uint_as_float(u << 16); }
__device__ __forceinline__ float bfhi(unsigned int u) { return __uint_as_float(u & 0xFFFF0000u); }

// ---------------------------------------------------------------------------
// CSR build (dst -> incoming edge list), shared by both layers.
// Self-loops are NOT processed by hist/scatter: the scan adds +1 per node
// and scan_bottom writes the self-loop deterministically at slot offs[n].
// hist/scatter batch 4 edges/thread -> 4 independent atomics in flight.
// ---------------------------------------------------------------------------
__global__ __launch_bounds__(256)
void hist_kernel(const int* __restrict__ ei, int* __restrict__ cnt, int E) {
    int base = (blockIdx.x * blockDim.x + threadIdx.x) * 4;
    if (base + 4 <= E) {
        int4 d4 = *reinterpret_cast<const int4*>(&ei[E + base]);
        atomicAdd(&cnt[d4.x], 1);
        atomicAdd(&cnt[d4.y], 1);
        atomicAdd(&cnt[d4.z], 1);
        atomicAdd(&cnt[d4.w], 1);
    } else {
        for (int e = base; e < E; ++e) atomicAdd(&cnt[ei[E + e]], 1);
    }
}

// ---- 3-phase device-wide exclusive scan over (cnt[N]+1) -> offs/cursor ----
#define SCB 256   // scan block size == elements per block

__global__ __launch_bounds__(SCB)
void scan_partial(const int* __restrict__ cnt, int* __restrict__ bsum, int N) {
    __shared__ int lds[SCB];
    int b = blockIdx.x, t = threadIdx.x;
    int i = b * SCB + t;
    int v = (i < N) ? cnt[i] + 1 : 0;     // +1 = self-loop
    lds[t] = v;
    __syncthreads();
    for (int off = SCB / 2; off >= 1; off >>= 1) {
        if (t < off) lds[t] += lds[t + off];
        __syncthreads();
    }
    if (t == 0) bsum[b] = lds[0];
}

__global__ __launch_bounds__(SCB)
void scan_top(int* __restrict__ bsum, int* __restrict__ base, int nb) {
    __shared__ int lds[SCB];
    int t = threadIdx.x;
    int v = (t < nb) ? bsum[t] : 0;
    lds[t] = v;
    __syncthreads();
    for (int off = 1; off < SCB; off <<= 1) {
        int u = (t >= off) ? lds[t - off] : 0;
        __syncthreads();
        lds[t] += u;
        __syncthreads();
    }
    if (t < nb) base[t] = lds[t] - v;   // exclusive
}

__global__ __launch_bounds__(SCB)
void scan_bottom(const int* __restrict__ cnt, const int* __restrict__ base,
                 int* __restrict__ offs, int* __restrict__ cursor,
                 int* __restrict__ csr, int N) {
    __shared__ int lds[SCB];
    int b = blockIdx.x, t = threadIdx.x;
    int i = b * SCB + t;
    int v = (i < N) ? cnt[i] + 1 : 0;     // +1 = self-loop
    lds[t] = v;
    __syncthreads();
    for (int off = 1; off < SCB; off <<= 1) {
        int u = (t >= off) ? lds[t - off] : 0;
        __syncthreads();
        lds[t] += u;
        __syncthreads();
    }
    int excl = base[b] + lds[t] - v;
    if (i < N) {
        offs[i] = excl;
        cursor[i] = excl + 1;   // slot 0 taken by the self-loop
        csr[excl] = i;          // self-loop written deterministically
    }
    if (i == N - 1) offs[N] = excl + v;
}

__global__ __launch_bounds__(256)
void scatter_kernel(const int* __restrict__ ei, int* __restrict__ cursor,
                    int* __restrict__ csr, int E) {
    int base = (blockIdx.x * blockDim.x + threadIdx.x) * 4;
    if (base + 4 <= E) {
        int4 s4 = *reinterpret_cast<const int4*>(&ei[base]);
        int4 d4 = *reinterpret_cast<const int4*>(&ei[E + base]);
        int p0 = atomicAdd(&cursor[d4.x], 1);
        int p1 = atomicAdd(&cursor[d4.y], 1);
        int p2 = atomicAdd(&cursor[d4.z], 1);
        int p3 = atomicAdd(&cursor[d4.w], 1);
        csr[p0] = s4.x;
        csr[p1] = s4.y;
        csr[p2] = s4.z;
        csr[p3] = s4.w;
    } else {
        for (int e = base; e < E; ++e) {
            int pos = atomicAdd(&cursor[ei[E + e]], 1);
            csr[pos] = ei[e];
        }
    }
}

// ---------------------------------------------------------------------------
// Layer 1 GEMM via split-bf16 MFMA: h1 = x @ W1, ~fp32 accuracy.
// h1 stored bf16; alpha scalars from full fp32 accumulator.
// ---------------------------------------------------------------------------
__global__ __launch_bounds__(256)
void gemm1_mfma(const float* __restrict__ x, const float* __restrict__ W,
                const float* __restrict__ a_src, const float* __restrict__ a_dst,
                unsigned short* __restrict__ h1b, float* __restrict__ as1,
                float* __restrict__ ad1, int N) {
    __shared__ unsigned short whi[FIN * HC1];   // 32 KB, fragment-ordered
    __shared__ unsigned short wlo[FIN * HC1];   // 32 KB
    int tid = threadIdx.x;

#pragma unroll
    for (int i = 0; i < 64; ++i) {
        int idx = tid + i * 256;            // 0..16383, coalesced
        int k = idx >> 7, c = idx & 127;
        float v = W[idx];
        unsigned short hb = f2bf_rne(v);
        unsigned short lb = f2bf_rne(v - bf2f(hb));
        int kb = k >> 5, kk = k & 31;
        int g = kk >> 3, j = kk & 7;
        int ct = c >> 4, li = c & 15;
        int off = ((kb * 8 + ct) * 64 + g * 16 + li) * 8 + j;
        whi[off] = hb;
        wlo[off] = lb;
    }

    int wid = tid >> 6, lane = tid & 63;
    int li = lane & 15, g = lane >> 4;
    int rowbase = blockIdx.x * 64 + wid * 16;

    int arow = rowbase + li;
    if (arow >= N) arow = N - 1;            // clamp; invalid rows never stored
    const float* xp = x + (long)arow * FIN + g * 8;
    bf16x8 Ahi[4], Alo[4];
#pragma unroll
    for (int kb = 0; kb < 4; ++kb) {
        float4 v0 = *reinterpret_cast<const float4*>(xp + kb * 32);
        float4 v1 = *reinterpret_cast<const float4*>(xp + kb * 32 + 4);
        float vs0 = v0.x, vs1 = v0.y, vs2 = v0.z, vs3 = v0.w;
        float vs4 = v1.x, vs5 = v1.y, vs6 = v1.z, vs7 = v1.w;
        bf16x8 h8, l8;
        unsigned short hb;
        hb = f2bf_rne(vs0); h8[0] = (short)hb; l8[0] = (short)f2bf_rne(vs0 - bf2f(hb));
        hb = f2bf_rne(vs1); h8[1] = (short)hb; l8[1] = (short)f2bf_rne(vs1 - bf2f(hb));
        hb = f2bf_rne(vs2); h8[2] = (short)hb; l8[2] = (short)f2bf_rne(vs2 - bf2f(hb));
        hb = f2bf_rne(vs3); h8[3] = (short)hb; l8[3] = (short)f2bf_rne(vs3 - bf2f(hb));
        hb = f2bf_rne(vs4); h8[4] = (short)hb; l8[4] = (short)f2bf_rne(vs4 - bf2f(hb));
        hb = f2bf_rne(vs5); h8[5] = (short)hb; l8[5] = (short)f2bf_rne(vs5 - bf2f(hb));
        hb = f2bf_rne(vs6); h8[6] = (short)hb; l8[6] = (short)f2bf_rne(vs6 - bf2f(hb));
        hb = f2bf_rne(vs7); h8[7] = (short)hb; l8[7] = (short)f2bf_rne(vs7 - bf2f(hb));
        Ahi[kb] = h8; Alo[kb] = l8;
    }

    float asr[8], adr[8];
#pragma unroll
    for (int ct = 0; ct < 8; ++ct) {
        asr[ct] = a_src[ct * 16 + li];
        adr[ct] = a_dst[ct * 16 + li];
    }

    __syncthreads();

    f32x4 acc[8];
#pragma unroll
    for (int ct = 0; ct < 8; ++ct) acc[ct] = (f32x4){0.f, 0.f, 0.f, 0.f};

#pragma unroll
    for (int kb = 0; kb < 4; ++kb) {
#pragma unroll
        for (int ct = 0; ct < 8; ++ct) {
            bf16x8 bh = *reinterpret_cast<const bf16x8*>(&whi[((kb * 8 + ct) * 64 + lane) * 8]);
            bf16x8 bl = *reinterpret_cast<const bf16x8*>(&wlo[((kb * 8 + ct) * 64 + lane) * 8]);
            acc[ct] = __builtin_amdgcn_mfma_f32_16x16x32_bf16(Alo[kb], bh, acc[ct], 0, 0, 0);
            acc[ct] = __builtin_amdgcn_mfma_f32_16x16x32_bf16(Ahi[kb], bl, acc[ct], 0, 0, 0);
            acc[ct] = __builtin_amdgcn_mfma_f32_16x16x32_bf16(Ahi[kb], bh, acc[ct], 0, 0, 0);
        }
    }

    // Epilogue: store h1 (bf16) + fused per-head alpha reductions (fp32).
#pragma unroll
    for (int q = 0; q < 4; ++q) {
        int n = rowbase + g * 4 + q;
        bool valid = (n < N);
        float p0s = 0.f, p1s = 0.f, p0d = 0.f, p1d = 0.f;
#pragma unroll
        for (int ct = 0; ct < 8; ++ct) {
            float h = acc[ct][q];
            if (valid) h1b[(long)n * HC1 + ct * 16 + li] = f2bf_rne(h);
            if (ct < 4) { p0s = fmaf(h, asr[ct], p0s); p0d = fmaf(h, adr[ct], p0d); }
            else        { p1s = fmaf(h, asr[ct], p1s); p1d = fmaf(h, adr[ct], p1d); }
        }
#pragma unroll
        for (int off = 8; off >= 1; off >>= 1) {
            p0s += __shfl_xor(p0s, off, 16);
            p1s += __shfl_xor(p1s, off, 16);
            p0d += __shfl_xor(p0d, off, 16);
            p1d += __shfl_xor(p1d, off, 16);
        }
        if (valid && li == 0) {
            as1[n * 2 + 0] = p0s; as1[n * 2 + 1] = p1s;
            ad1[n * 2 + 0] = p0d; ad1[n * 2 + 1] = p1d;
        }
    }
}

// ---------------------------------------------------------------------------
// Layer 1 scores: 16 lanes per node, no barriers/atomics.
// ---------------------------------------------------------------------------
__global__ __launch_bounds__(256)
void scores1(const int* __restrict__ offs, const int* __restrict__ csr,
             const float* __restrict__ as_arr, const float* __restrict__ ad_arr,
             float2* __restrict__ pe, float2* __restrict__ rden, int N) {
    int n = (blockIdx.x * blockDim.x + threadIdx.x) >> 4;
    int l = threadIdx.x & 15;
    if (n >= N) return;
    int s0 = offs[n], s1 = offs[n + 1];
    float ad0 = ad_arr[2 * n], ad1v = ad_arr[2 * n + 1];

    float m0 = -1e30f, m1 = -1e30f;
    for (int i = s0 + l; i < s1; i += 16) {
        int s = csr[i];
        float2 a = *reinterpret_cast<const float2*>(&as_arr[2 * s]);
        float v0 = a.x + ad0; v0 = (v0 >= 0.f) ? v0 : NEG_SLOPE * v0;
        float v1 = a.y + ad1v; v1 = (v1 >= 0.f) ? v1 : NEG_SLOPE * v1;
        m0 = fmaxf(m0, v0); m1 = fmaxf(m1, v1);
    }
#pragma unroll
    for (int off = 8; off >= 1; off >>= 1) {
        m0 = fmaxf(m0, __shfl_xor(m0, off, 16));
        m1 = fmaxf(m1, __shfl_xor(m1, off, 16));
    }
    float d0 = 0.f, d1 = 0.f;
    for (int i = s0 + l; i < s1; i += 16) {
        int s = csr[i];
        float2 a = *reinterpret_cast<const float2*>(&as_arr[2 * s]);
        float v0 = a.x + ad0; v0 = (v0 >= 0.f) ? v0 : NEG_SLOPE * v0;
        float v1 = a.y + ad1v; v1 = (v1 >= 0.f) ? v1 : NEG_SLOPE * v1;
        float p0 = __expf(v0 - m0), p1 = __expf(v1 - m1);
        d0 += p0; d1 += p1;
        pe[i] = make_float2(p0, p1);
    }
#pragma unroll
    for (int off = 8; off >= 1; off >>= 1) {
        d0 += __shfl_xor(d0, off, 16);
        d1 += __shfl_xor(d1, off, 16);
    }
    if (l == 0) rden[n] = make_float2(1.f / (d0 + 1e-16f), 1.f / (d1 + 1e-16f));
}

// ---------------------------------------------------------------------------
// Layer 1 gather: pure SpMM over bf16 h1 rows (256 B each).
// ---------------------------------------------------------------------------
__global__ __launch_bounds__(256)
void gather1(const int* __restrict__ offs, const int* __restrict__ csr,
             const float2* __restrict__ pe, const float2* __restrict__ rden,
             const unsigned short* __restrict__ h1b, const float* __restrict__ b1,
             float* __restrict__ h2, int N) {
    int g = threadIdx.x >> 5;        // 0..7 node-group in block
    int l = threadIdx.x & 31;        // lane in group: cols 4l..4l+3
    int n = blockIdx.x * 8 + g;
    if (n >= N) return;
    int head = l >> 4;
    int s0 = offs[n], s1 = offs[n + 1];

    float4 acc = make_float4(0.f, 0.f, 0.f, 0.f);
    int i = s0;
    for (; i + 4 <= s1; i += 4) {
        int sa = csr[i], sb = csr[i + 1], sc = csr[i + 2], sd = csr[i + 3];
        float2 pa = pe[i], pb = pe[i + 1], pc = pe[i + 2], pd = pe[i + 3];
        uint2 ua = *reinterpret_cast<const uint2*>(&h1b[((long)sa << 7) + 4 * l]);
        uint2 ub = *reinterpret_cast<const uint2*>(&h1b[((long)sb << 7) + 4 * l]);
        uint2 uc = *reinterpret_cast<const uint2*>(&h1b[((long)sc << 7) + 4 * l]);
        uint2 ud = *reinterpret_cast<const uint2*>(&h1b[((long)sd << 7) + 4 * l]);
        float wa = head ? pa.y : pa.x;
        float wb = head ? pb.y : pb.x;
        float wc = head ? pc.y : pc.x;
        float wd = head ? pd.y : pd.x;
        acc.x = fmaf(bflo(ua.x), wa, acc.x); acc.y = fmaf(bfhi(ua.x), wa, acc.y);
        acc.z = fmaf(bflo(ua.y), wa, acc.z); acc.w = fmaf(bfhi(ua.y), wa, acc.w);
        acc.x = fmaf(bflo(ub.x), wb, acc.x); acc.y = fmaf(bfhi(ub.x), wb, acc.y);
        acc.z = fmaf(bflo(ub.y), wb, acc.z); acc.w = fmaf(bfhi(ub.y), wb, acc.w);
        acc.x = fmaf(bflo(uc.x), wc, acc.x); acc.y = fmaf(bfhi(uc.x), wc, acc.y);
        acc.z = fmaf(bflo(uc.y), wc, acc.z); acc.w = fmaf(bfhi(uc.y), wc, acc.w);
        acc.x = fmaf(bflo(ud.x), wd, acc.x); acc.y = fmaf(bfhi(ud.x), wd, acc.y);
        acc.z = fmaf(bflo(ud.y), wd, acc.z); acc.w = fmaf(bfhi(ud.y), wd, acc.w);
    }
    for (; i < s1; ++i) {
        int s = csr[i];
        float2 p2 = pe[i];
        float w = head ? p2.y : p2.x;
        uint2 u = *reinterpret_cast<const uint2*>(&h1b[((long)s << 7) + 4 * l]);
        acc.x = fmaf(bflo(u.x), w, acc.x); acc.y = fmaf(bfhi(u.x), w, acc.y);
        acc.z = fmaf(bflo(u.y), w, acc.z); acc.w = fmaf(bfhi(u.y), w, acc.w);
    }
    float2 rd = rden[n];
    float r = head ? rd.y : rd.x;
    int col = 4 * l;
    float4 bb = *reinterpret_cast<const float4*>(&b1[col]);
    float4 o;
    o.x = acc.x * r + bb.x; o.y = acc.y * r + bb.y;
    o.z = acc.z * r + bb.z; o.w = acc.w * r + bb.w;
    o.x = (o.x > 0.f) ? o.x : expm1f(o.x);
    o.y = (o.y > 0.f) ? o.y : expm1f(o.y);
    o.z = (o.z > 0.f) ? o.z : expm1f(o.z);
    o.w = (o.w > 0.f) ? o.w : expm1f(o.w);
    *reinterpret_cast<float4*>(&h2[((long)n << 7) + col]) = o;
}

// ---------------------------------------------------------------------------
// Layer 2 GEMM
// ---------------------------------------------------------------------------
__global__ __launch_bounds__(256)
void gemm2_alpha(const float* __restrict__ h2, const float* __restrict__ W2,
                 const float* __restrict__ a_src, const float* __restrict__ a_dst,
                 float* __restrict__ z, float* __restrict__ as2, float* __restrict__ ad2,
                 int N) {
    __shared__ float hs[16][FIN + 4];
    __shared__ float ws[FIN * NCLS];
    int tid = threadIdx.x;
    int n0 = blockIdx.x * 16;
    for (int i = tid; i < FIN * NCLS; i += 256) ws[i] = W2[i];
    for (int i = tid; i < 16 * FIN; i += 256) {
        int r = i >> 7, c = i & 127;
        int n = n0 + r;
        hs[r][c] = (n < N) ? h2[(long)n * FIN + c] : 0.f;
    }
    __syncthreads();

    int r = tid >> 4, c = tid & 15;
    int n = n0 + r;
    float acc = 0.f;
#pragma unroll 4
    for (int k = 0; k < FIN; ++k)
        acc = fmaf(hs[r][k], ws[k * NCLS + c], acc);

    float sa = acc * a_src[c];
    float da = acc * a_dst[c];
    for (int off = 8; off >= 1; off >>= 1) {
        sa += __shfl_xor(sa, off, 16);
        da += __shfl_xor(da, off, 16);
    }
    if (n < N) {
        z[n * NCLS + c] = acc;
        if (c == 0) { as2[n] = sa; ad2[n] = da; }
    }
}

// ---------------------------------------------------------------------------
// Layer 2 scores (H=1): 16 lanes per node.
// ---------------------------------------------------------------------------
__global__ __launch_bounds__(256)
void scores2(const int* __restrict__ offs, const int* __restrict__ csr,
             const float* __restrict__ as2, const float* __restrict__ ad2,
             float* __restrict__ pe2, float* __restrict__ rden2, int N) {
    int n = (blockIdx.x * blockDim.x + threadIdx.x) >> 4;
    int l = threadIdx.x & 15;
    if (n >= N) return;
    int s0 = offs[n], s1 = offs[n + 1];
    float adn = ad2[n];

    float m = -1e30f;
    for (int i = s0 + l; i < s1; i += 16) {
        float v = as2[csr[i]] + adn;
        v = (v >= 0.f) ? v : NEG_SLOPE * v;
        m = fmaxf(m, v);
    }
#pragma unroll
    for (int off = 8; off >= 1; off >>= 1) m = fmaxf(m, __shfl_xor(m, off, 16));
    float d = 0.f;
    for (int i = s0 + l; i < s1; i += 16) {
        float v = as2[csr[i]] + adn;
        v = (v >= 0.f) ? v : NEG_SLOPE * v;
        float p = __expf(v - m);
        d += p;
        pe2[i] = p;
    }
#pragma unroll
    for (int off = 8; off >= 1; off >>= 1) d += __shfl_xor(d, off, 16);
    if (l == 0) rden2[n] = 1.f / (d + 1e-16f);
}

// ---------------------------------------------------------------------------
// Layer 2 gather + bias + log_softmax. 16 lanes per node (lane = class).
// ---------------------------------------------------------------------------
__global__ __launch_bounds__(256)
void gather2(const int* __restrict__ offs, const int* __restrict__ csr,
             const float* __restrict__ pe2, const float* __restrict__ rden2,
             const float* __restrict__ z, const float* __restrict__ b2,
             float* __restrict__ out, int N) {
    int g = threadIdx.x >> 4;
    int l = threadIdx.x & 15;
    int n = blockIdx.x * 16 + g;
    if (n >= N) return;
    int s0 = offs[n], s1 = offs[n + 1];

    float acc = 0.f;
    int i = s0;
    for (; i + 4 <= s1; i += 4) {
        int sa = csr[i], sb = csr[i + 1], sc = csr[i + 2], sd = csr[i + 3];
        float pa = pe2[i], pb = pe2[i + 1], pc = pe2[i + 2], pd = pe2[i + 3];
        float za = z[sa * NCLS + l];
        float zb = z[sb * NCLS + l];
        float zc = z[sc * NCLS + l];
        float zd = z[sd * NCLS + l];
        acc = fmaf(za, pa, acc);
        acc = fmaf(zb, pb, acc);
        acc = fmaf(zc, pc, acc);
        acc = fmaf(zd, pd, acc);
    }
    for (; i < s1; ++i) acc = fmaf(z[csr[i] * NCLS + l], pe2[i], acc);

    float o = acc * rden2[n] + b2[l];

    float mx = o;
#pragma unroll
    for (int off = 8; off >= 1; off >>= 1) mx = fmaxf(mx, __shfl_xor(mx, off, 16));
    float ex = __expf(o - mx);
    float sum = ex;
#pragma unroll
    for (int off = 8; off >= 1; off >>= 1) sum += __shfl_xor(sum, off, 16);
    out[(long)n * NCLS + l] = o - mx - __logf(sum);
}

// ---------------------------------------------------------------------------
extern "C" void kernel_launch(void* const* d_in, const int* in_sizes, int n_in,
                              void* d_out, int out_size, void* d_ws, size_t ws_size,
                              hipStream_t stream) {
    const float* x        = (const float*)d_in[0];
    const int*   ei       = (const int*)  d_in[1];
    // d_in[2] = edge_attr (unused by reference)
    const float* W1       = (const float*)d_in[3];
    const float* att_src1 = (const float*)d_in[4];
    const float* att_dst1 = (const float*)d_in[5];
    const float* b1       = (const float*)d_in[6];
    const float* W2       = (const float*)d_in[7];
    const float* att_src2 = (const float*)d_in[8];
    const float* att_dst2 = (const float*)d_in[9];
    const float* b2       = (const float*)d_in[10];
    float* out = (float*)d_out;

    const int N = in_sizes[0] / FIN;        // 50000
    const int E = in_sizes[1] / 2;          // 800000
    const int Etot = E + N;                 // self-loops included
    const int nb = (N + SCB - 1) / SCB;     // scan blocks (196)

    // Workspace layout (bytes), with aliasing for layer-2 temporaries
    char* ws = (char*)d_ws;
    size_t off = 0;
    auto alloc = [&](size_t bytes) { char* p = ws + off; off += (bytes + 255) & ~(size_t)255; return p; };
    int*    cnt    = (int*)   alloc((size_t)N * 4);
    int*    offs   = (int*)   alloc((size_t)(N + 1) * 4);
    int*    cursor = (int*)   alloc((size_t)N * 4);
    int*    csr    = (int*)   alloc((size_t)Etot * 4);
    int*    bsum   = (int*)   alloc((size_t)nb * 4);
    int*    bbase  = (int*)   alloc((size_t)nb * 4);
    unsigned short* h1b = (unsigned short*)alloc((size_t)N * HC1 * 2);  // bf16
    float*  h2     = (float*) alloc((size_t)N * HC1 * 4);
    float*  z      = (float*) alloc((size_t)N * NCLS * 4);
    float2* pe     = (float2*)alloc((size_t)Etot * 8);      // layer2: pe2 aliases pe
    float2* rden   = (float2*)alloc((size_t)N * 8);         // layer2: rden2 aliases
    float*  as1    = (float*) alloc((size_t)N * 2 * 4);     // layer2: as2 aliases
    float*  ad1    = (float*) alloc((size_t)N * 2 * 4);     // layer2: ad2 aliases
    (void)ws_size;

    float* pe2   = (float*)pe;    // safe: gather1 (reads pe) precedes scores2
    float* rden2 = (float*)rden;
    float* as2   = as1;
    float* ad2   = ad1;

    hipMemsetAsync(cnt, 0, (size_t)N * 4, stream);

    int tb = 256;
    int eb4 = (E / 4 + tb - 1) / tb;        // 4 edges per thread
    hist_kernel<<<eb4, tb, 0, stream>>>(ei, cnt, E);
    scan_partial<<<nb, SCB, 0, stream>>>(cnt, bsum, N);
    scan_top<<<1, SCB, 0, stream>>>(bsum, bbase, nb);
    scan_bottom<<<nb, SCB, 0, stream>>>(cnt, bbase, offs, cursor, csr, N);
    scatter_kernel<<<eb4, tb, 0, stream>>>(ei, cursor, csr, E);

    gemm1_mfma<<<(N + 63) / 64, 256, 0, stream>>>(
        x, W1, att_src1, att_dst1, h1b, as1, ad1, N);
    scores1<<<(N + 15) / 16, 256, 0, stream>>>(offs, csr, as1, ad1, pe, rden, N);
    gather1<<<(N + 7) / 8, 256, 0, stream>>>(offs, csr, pe, rden, h1b, b1, h2, N);

    gemm2_alpha<<<(N + 15) / 16, 256, 0, stream>>>(
        h2, W2, att_src2, att_dst2, z, as2, ad2, N);
    scores2<<<(N + 15) / 16, 256, 0, stream>>>(offs, csr, as2, ad2, pe2, rden2, N);
    gather2<<<(N + 15) / 16, 256, 0, stream>>>(offs, csr, pe2, rden2, z, b2, out, N);
}

// Round 8
// 156.071 us; speedup vs baseline: 3.0287x; 1.3511x over previous
//
#include <hip/hip_runtime.h>
#include <math.h>

// Problem constants (match reference)
#define FIN   128
#define HC1   128   // H*C for layer 1
#define NCLS  16
#define NEG_SLOPE 0.2f

typedef __attribute__((ext_vector_type(8))) short bf16x8;
typedef __attribute__((ext_vector_type(4))) float f32x4;

__device__ __forceinline__ unsigned short f2bf_rne(float f) {
    unsigned int u = __float_as_uint(f);
    unsigned int r = u + 0x7FFFu + ((u >> 16) & 1u);
    return (unsigned short)(r >> 16);
}
__device__ __forceinline__ float bf2f(unsigned short h) {
    return __uint_as_float(((unsigned int)h) << 16);
}
__device__ __forceinline__ float bflo(unsigned int u) { return __uint_as_float(u << 16); }
__device__ __forceinline__ float bfhi(unsigned int u) { return __uint_as_float(u & 0xFFFF0000u); }

// ---------------------------------------------------------------------------
// CSR build via two-level bucket sort (bucket = dst>>8). Dense writes:
// no per-edge global atomics, no random 4B scatter, no device-wide scan.
// Self-loops are NOT in the CSR; scores/gather handle them analytically.
// ---------------------------------------------------------------------------
#define EPB 4096   // edges per block in bcnt/binA

__global__ __launch_bounds__(256)
void bcnt_kernel(const int* __restrict__ ei, int* __restrict__ bucket_cnt,
                 int E, int NB) {
    __shared__ int h[256];
    int tid = threadIdx.x;
    h[tid] = 0;
    __syncthreads();
    int base = blockIdx.x * EPB;
#pragma unroll
    for (int j = 0; j < EPB / 256; ++j) {
        int e = base + j * 256 + tid;
        if (e < E) atomicAdd(&h[ei[E + e] >> 8], 1);
    }
    __syncthreads();
    if (tid < NB && h[tid]) atomicAdd(&bucket_cnt[tid], h[tid]);
}

__global__ __launch_bounds__(256)
void bscan_kernel(const int* __restrict__ bucket_cnt, int* __restrict__ bucket_base,
                  int* __restrict__ bucket_cursor, int NB) {
    __shared__ int lds[256];
    int t = threadIdx.x;
    int v = (t < NB) ? bucket_cnt[t] : 0;
    lds[t] = v;
    __syncthreads();
    for (int off = 1; off < 256; off <<= 1) {
        int u = (t >= off) ? lds[t - off] : 0;
        __syncthreads();
        lds[t] += u;
        __syncthreads();
    }
    int excl = lds[t] - v;
    if (t < NB) { bucket_base[t] = excl; bucket_cursor[t] = excl; }
    if (t == 255) bucket_base[NB] = lds[255];   // == E
}

__global__ __launch_bounds__(256)
void binA_kernel(const int* __restrict__ ei, int* __restrict__ bucket_cursor,
                 int2* __restrict__ tmp, int E, int NB) {
    __shared__ int h[256];    // counts, then local cursors
    __shared__ int bb[256];   // block's global base per bucket
    int tid = threadIdx.x;
    h[tid] = 0;
    __syncthreads();
    int base = blockIdx.x * EPB;
    int src[EPB / 256], dst[EPB / 256];
#pragma unroll
    for (int j = 0; j < EPB / 256; ++j) {
        int e = base + j * 256 + tid;
        if (e < E) { src[j] = ei[e]; dst[j] = ei[E + e]; }
        else dst[j] = -1;
    }
#pragma unroll
    for (int j = 0; j < EPB / 256; ++j)
        if (dst[j] >= 0) atomicAdd(&h[dst[j] >> 8], 1);
    __syncthreads();
    if (tid < NB) {
        int c = h[tid];
        bb[tid] = c ? atomicAdd(&bucket_cursor[tid], c) : 0;
        h[tid] = 0;
    }
    __syncthreads();
#pragma unroll
    for (int j = 0; j < EPB / 256; ++j) {
        if (dst[j] >= 0) {
            int b = dst[j] >> 8;
            int r = atomicAdd(&h[b], 1);
            tmp[bb[b] + r] = make_int2(src[j], dst[j]);
        }
    }
}

// One block per bucket: sorts its bucket by node, writes csr densely and
// emits eoffs (global CSR offsets) directly.
__global__ __launch_bounds__(256)
void binB_kernel(const int2* __restrict__ tmp, const int* __restrict__ bucket_base,
                 int* __restrict__ csr, int* __restrict__ eoffs, int E, int N) {
    __shared__ int cnt[256];
    __shared__ int lds[256];
    __shared__ int cur[256];
    int b = blockIdx.x, t = threadIdx.x;
    int lo = bucket_base[b], hi = bucket_base[b + 1];
    cnt[t] = 0;
    __syncthreads();
    for (int i = lo + t; i < hi; i += 256)
        atomicAdd(&cnt[tmp[i].y & 255], 1);
    __syncthreads();
    int v = cnt[t];
    lds[t] = v;
    __syncthreads();
    for (int off = 1; off < 256; off <<= 1) {
        int u = (t >= off) ? lds[t - off] : 0;
        __syncthreads();
        lds[t] += u;
        __syncthreads();
    }
    int excl = lds[t] - v;
    int node = b * 256 + t;
    if (node < N) eoffs[node] = lo + excl;
    if (b == 0 && t == 0) eoffs[N] = E;
    cur[t] = lo + excl;
    __syncthreads();
    for (int i = lo + t; i < hi; i += 256) {
        int2 e = tmp[i];
        int p = atomicAdd(&cur[e.y & 255], 1);
        csr[p] = e.x;
    }
}

// ---------------------------------------------------------------------------
// Layer 1 GEMM via split-bf16 MFMA: h1 = x @ W1, ~fp32 accuracy.
// h1 stored bf16; alpha scalars from full fp32 accumulator.
// ---------------------------------------------------------------------------
__global__ __launch_bounds__(256)
void gemm1_mfma(const float* __restrict__ x, const float* __restrict__ W,
                const float* __restrict__ a_src, const float* __restrict__ a_dst,
                unsigned short* __restrict__ h1b, float* __restrict__ as1,
                float* __restrict__ ad1, int N) {
    __shared__ unsigned short whi[FIN * HC1];   // 32 KB, fragment-ordered
    __shared__ unsigned short wlo[FIN * HC1];   // 32 KB
    int tid = threadIdx.x;

#pragma unroll
    for (int i = 0; i < 64; ++i) {
        int idx = tid + i * 256;            // 0..16383, coalesced
        int k = idx >> 7, c = idx & 127;
        float v = W[idx];
        unsigned short hb = f2bf_rne(v);
        unsigned short lb = f2bf_rne(v - bf2f(hb));
        int kb = k >> 5, kk = k & 31;
        int g = kk >> 3, j = kk & 7;
        int ct = c >> 4, li = c & 15;
        int off = ((kb * 8 + ct) * 64 + g * 16 + li) * 8 + j;
        whi[off] = hb;
        wlo[off] = lb;
    }

    int wid = tid >> 6, lane = tid & 63;
    int li = lane & 15, g = lane >> 4;
    int rowbase = blockIdx.x * 64 + wid * 16;

    int arow = rowbase + li;
    if (arow >= N) arow = N - 1;            // clamp; invalid rows never stored
    const float* xp = x + (long)arow * FIN + g * 8;
    bf16x8 Ahi[4], Alo[4];
#pragma unroll
    for (int kb = 0; kb < 4; ++kb) {
        float4 v0 = *reinterpret_cast<const float4*>(xp + kb * 32);
        float4 v1 = *reinterpret_cast<const float4*>(xp + kb * 32 + 4);
        float vs0 = v0.x, vs1 = v0.y, vs2 = v0.z, vs3 = v0.w;
        float vs4 = v1.x, vs5 = v1.y, vs6 = v1.z, vs7 = v1.w;
        bf16x8 h8, l8;
        unsigned short hb;
        hb = f2bf_rne(vs0); h8[0] = (short)hb; l8[0] = (short)f2bf_rne(vs0 - bf2f(hb));
        hb = f2bf_rne(vs1); h8[1] = (short)hb; l8[1] = (short)f2bf_rne(vs1 - bf2f(hb));
        hb = f2bf_rne(vs2); h8[2] = (short)hb; l8[2] = (short)f2bf_rne(vs2 - bf2f(hb));
        hb = f2bf_rne(vs3); h8[3] = (short)hb; l8[3] = (short)f2bf_rne(vs3 - bf2f(hb));
        hb = f2bf_rne(vs4); h8[4] = (short)hb; l8[4] = (short)f2bf_rne(vs4 - bf2f(hb));
        hb = f2bf_rne(vs5); h8[5] = (short)hb; l8[5] = (short)f2bf_rne(vs5 - bf2f(hb));
        hb = f2bf_rne(vs6); h8[6] = (short)hb; l8[6] = (short)f2bf_rne(vs6 - bf2f(hb));
        hb = f2bf_rne(vs7); h8[7] = (short)hb; l8[7] = (short)f2bf_rne(vs7 - bf2f(hb));
        Ahi[kb] = h8; Alo[kb] = l8;
    }

    float asr[8], adr[8];
#pragma unroll
    for (int ct = 0; ct < 8; ++ct) {
        asr[ct] = a_src[ct * 16 + li];
        adr[ct] = a_dst[ct * 16 + li];
    }

    __syncthreads();

    f32x4 acc[8];
#pragma unroll
    for (int ct = 0; ct < 8; ++ct) acc[ct] = (f32x4){0.f, 0.f, 0.f, 0.f};

#pragma unroll
    for (int kb = 0; kb < 4; ++kb) {
#pragma unroll
        for (int ct = 0; ct < 8; ++ct) {
            bf16x8 bh = *reinterpret_cast<const bf16x8*>(&whi[((kb * 8 + ct) * 64 + lane) * 8]);
            bf16x8 bl = *reinterpret_cast<const bf16x8*>(&wlo[((kb * 8 + ct) * 64 + lane) * 8]);
            acc[ct] = __builtin_amdgcn_mfma_f32_16x16x32_bf16(Alo[kb], bh, acc[ct], 0, 0, 0);
            acc[ct] = __builtin_amdgcn_mfma_f32_16x16x32_bf16(Ahi[kb], bl, acc[ct], 0, 0, 0);
            acc[ct] = __builtin_amdgcn_mfma_f32_16x16x32_bf16(Ahi[kb], bh, acc[ct], 0, 0, 0);
        }
    }

    // Epilogue: store h1 (bf16) + fused per-head alpha reductions (fp32).
#pragma unroll
    for (int q = 0; q < 4; ++q) {
        int n = rowbase + g * 4 + q;
        bool valid = (n < N);
        float p0s = 0.f, p1s = 0.f, p0d = 0.f, p1d = 0.f;
#pragma unroll
        for (int ct = 0; ct < 8; ++ct) {
            float h = acc[ct][q];
            if (valid) h1b[(long)n * HC1 + ct * 16 + li] = f2bf_rne(h);
            if (ct < 4) { p0s = fmaf(h, asr[ct], p0s); p0d = fmaf(h, adr[ct], p0d); }
            else        { p1s = fmaf(h, asr[ct], p1s); p1d = fmaf(h, adr[ct], p1d); }
        }
#pragma unroll
        for (int off = 8; off >= 1; off >>= 1) {
            p0s += __shfl_xor(p0s, off, 16);
            p1s += __shfl_xor(p1s, off, 16);
            p0d += __shfl_xor(p0d, off, 16);
            p1d += __shfl_xor(p1d, off, 16);
        }
        if (valid && li == 0) {
            as1[n * 2 + 0] = p0s; as1[n * 2 + 1] = p1s;
            ad1[n * 2 + 0] = p0d; ad1[n * 2 + 1] = p1d;
        }
    }
}

// ---------------------------------------------------------------------------
// Layer 1 scores: 16 lanes per node. Self-loop handled analytically:
// v_self = leakyrelu(as[n]+ad[n]); p_self kept per node (not in pe).
// ---------------------------------------------------------------------------
__global__ __launch_bounds__(256)
void scores1(const int* __restrict__ eoffs, const int* __restrict__ csr,
             const float* __restrict__ as_arr, const float* __restrict__ ad_arr,
             float2* __restrict__ pe, float2* __restrict__ rden,
             float2* __restrict__ pself, int N) {
    int n = (blockIdx.x * blockDim.x + threadIdx.x) >> 4;
    int l = threadIdx.x & 15;
    if (n >= N) return;
    int s0 = eoffs[n], s1 = eoffs[n + 1];
    float2 aself = *reinterpret_cast<const float2*>(&as_arr[2 * n]);
    float ad0 = ad_arr[2 * n], ad1v = ad_arr[2 * n + 1];
    float vs0 = aself.x + ad0;  vs0 = (vs0 >= 0.f) ? vs0 : NEG_SLOPE * vs0;
    float vs1 = aself.y + ad1v; vs1 = (vs1 >= 0.f) ? vs1 : NEG_SLOPE * vs1;

    float m0 = vs0, m1 = vs1;
    for (int i = s0 + l; i < s1; i += 16) {
        int s = csr[i];
        float2 a = *reinterpret_cast<const float2*>(&as_arr[2 * s]);
        float v0 = a.x + ad0; v0 = (v0 >= 0.f) ? v0 : NEG_SLOPE * v0;
        float v1 = a.y + ad1v; v1 = (v1 >= 0.f) ? v1 : NEG_SLOPE * v1;
        m0 = fmaxf(m0, v0); m1 = fmaxf(m1, v1);
    }
#pragma unroll
    for (int off = 8; off >= 1; off >>= 1) {
        m0 = fmaxf(m0, __shfl_xor(m0, off, 16));
        m1 = fmaxf(m1, __shfl_xor(m1, off, 16));
    }
    float d0 = 0.f, d1 = 0.f;
    for (int i = s0 + l; i < s1; i += 16) {
        int s = csr[i];
        float2 a = *reinterpret_cast<const float2*>(&as_arr[2 * s]);
        float v0 = a.x + ad0; v0 = (v0 >= 0.f) ? v0 : NEG_SLOPE * v0;
        float v1 = a.y + ad1v; v1 = (v1 >= 0.f) ? v1 : NEG_SLOPE * v1;
        float p0 = __expf(v0 - m0), p1 = __expf(v1 - m1);
        d0 += p0; d1 += p1;
        pe[i] = make_float2(p0, p1);
    }
#pragma unroll
    for (int off = 8; off >= 1; off >>= 1) {
        d0 += __shfl_xor(d0, off, 16);
        d1 += __shfl_xor(d1, off, 16);
    }
    float ps0 = __expf(vs0 - m0), ps1 = __expf(vs1 - m1);
    d0 += ps0; d1 += ps1;
    if (l == 0) {
        rden[n] = make_float2(1.f / (d0 + 1e-16f), 1.f / (d1 + 1e-16f));
        pself[n] = make_float2(ps0, ps1);
    }
}

// ---------------------------------------------------------------------------
// Layer 1 gather: SpMM over bf16 h1 rows; acc seeded with p_self * h1[n].
// ---------------------------------------------------------------------------
__global__ __launch_bounds__(256)
void gather1(const int* __restrict__ eoffs, const int* __restrict__ csr,
             const float2* __restrict__ pe, const float2* __restrict__ rden,
             const float2* __restrict__ pself,
             const unsigned short* __restrict__ h1b, const float* __restrict__ b1,
             float* __restrict__ h2, int N) {
    int g = threadIdx.x >> 5;        // 0..7 node-group in block
    int l = threadIdx.x & 31;        // lane in group: cols 4l..4l+3
    int n = blockIdx.x * 8 + g;
    if (n >= N) return;
    int head = l >> 4;
    int s0 = eoffs[n], s1 = eoffs[n + 1];

    float2 ps2 = pself[n];
    float psf = head ? ps2.y : ps2.x;
    uint2 us = *reinterpret_cast<const uint2*>(&h1b[((long)n << 7) + 4 * l]);
    float4 acc;
    acc.x = bflo(us.x) * psf; acc.y = bfhi(us.x) * psf;
    acc.z = bflo(us.y) * psf; acc.w = bfhi(us.y) * psf;

    int i = s0;
    for (; i + 4 <= s1; i += 4) {
        int sa = csr[i], sb = csr[i + 1], sc = csr[i + 2], sd = csr[i + 3];
        float2 pa = pe[i], pb = pe[i + 1], pc = pe[i + 2], pd = pe[i + 3];
        uint2 ua = *reinterpret_cast<const uint2*>(&h1b[((long)sa << 7) + 4 * l]);
        uint2 ub = *reinterpret_cast<const uint2*>(&h1b[((long)sb << 7) + 4 * l]);
        uint2 uc = *reinterpret_cast<const uint2*>(&h1b[((long)sc << 7) + 4 * l]);
        uint2 ud = *reinterpret_cast<const uint2*>(&h1b[((long)sd << 7) + 4 * l]);
        float wa = head ? pa.y : pa.x;
        float wb = head ? pb.y : pb.x;
        float wc = head ? pc.y : pc.x;
        float wd = head ? pd.y : pd.x;
        acc.x = fmaf(bflo(ua.x), wa, acc.x); acc.y = fmaf(bfhi(ua.x), wa, acc.y);
        acc.z = fmaf(bflo(ua.y), wa, acc.z); acc.w = fmaf(bfhi(ua.y), wa, acc.w);
        acc.x = fmaf(bflo(ub.x), wb, acc.x); acc.y = fmaf(bfhi(ub.x), wb, acc.y);
        acc.z = fmaf(bflo(ub.y), wb, acc.z); acc.w = fmaf(bfhi(ub.y), wb, acc.w);
        acc.x = fmaf(bflo(uc.x), wc, acc.x); acc.y = fmaf(bfhi(uc.x), wc, acc.y);
        acc.z = fmaf(bflo(uc.y), wc, acc.z); acc.w = fmaf(bfhi(uc.y), wc, acc.w);
        acc.x = fmaf(bflo(ud.x), wd, acc.x); acc.y = fmaf(bfhi(ud.x), wd, acc.y);
        acc.z = fmaf(bflo(ud.y), wd, acc.z); acc.w = fmaf(bfhi(ud.y), wd, acc.w);
    }
    for (; i < s1; ++i) {
        int s = csr[i];
        float2 p2 = pe[i];
        float w = head ? p2.y : p2.x;
        uint2 u = *reinterpret_cast<const uint2*>(&h1b[((long)s << 7) + 4 * l]);
        acc.x = fmaf(bflo(u.x), w, acc.x); acc.y = fmaf(bfhi(u.x), w, acc.y);
        acc.z = fmaf(bflo(u.y), w, acc.z); acc.w = fmaf(bfhi(u.y), w, acc.w);
    }
    float2 rd = rden[n];
    float r = head ? rd.y : rd.x;
    int col = 4 * l;
    float4 bb = *reinterpret_cast<const float4*>(&b1[col]);
    float4 o;
    o.x = acc.x * r + bb.x; o.y = acc.y * r + bb.y;
    o.z = acc.z * r + bb.z; o.w = acc.w * r + bb.w;
    o.x = (o.x > 0.f) ? o.x : expm1f(o.x);
    o.y = (o.y > 0.f) ? o.y : expm1f(o.y);
    o.z = (o.z > 0.f) ? o.z : expm1f(o.z);
    o.w = (o.w > 0.f) ? o.w : expm1f(o.w);
    *reinterpret_cast<float4*>(&h2[((long)n << 7) + col]) = o;
}

// ---------------------------------------------------------------------------
// Layer 2 GEMM
// ---------------------------------------------------------------------------
__global__ __launch_bounds__(256)
void gemm2_alpha(const float* __restrict__ h2, const float* __restrict__ W2,
                 const float* __restrict__ a_src, const float* __restrict__ a_dst,
                 float* __restrict__ z, float* __restrict__ as2, float* __restrict__ ad2,
                 int N) {
    __shared__ float hs[16][FIN + 4];
    __shared__ float ws[FIN * NCLS];
    int tid = threadIdx.x;
    int n0 = blockIdx.x * 16;
    for (int i = tid; i < FIN * NCLS; i += 256) ws[i] = W2[i];
    for (int i = tid; i < 16 * FIN; i += 256) {
        int r = i >> 7, c = i & 127;
        int n = n0 + r;
        hs[r][c] = (n < N) ? h2[(long)n * FIN + c] : 0.f;
    }
    __syncthreads();

    int r = tid >> 4, c = tid & 15;
    int n = n0 + r;
    float acc = 0.f;
#pragma unroll 4
    for (int k = 0; k < FIN; ++k)
        acc = fmaf(hs[r][k], ws[k * NCLS + c], acc);

    float sa = acc * a_src[c];
    float da = acc * a_dst[c];
    for (int off = 8; off >= 1; off >>= 1) {
        sa += __shfl_xor(sa, off, 16);
        da += __shfl_xor(da, off, 16);
    }
    if (n < N) {
        z[n * NCLS + c] = acc;
        if (c == 0) { as2[n] = sa; ad2[n] = da; }
    }
}

// ---------------------------------------------------------------------------
// Layer 2 scores (H=1): 16 lanes per node, analytic self-loop.
// ---------------------------------------------------------------------------
__global__ __launch_bounds__(256)
void scores2(const int* __restrict__ eoffs, const int* __restrict__ csr,
             const float* __restrict__ as2, const float* __restrict__ ad2,
             float* __restrict__ pe2, float* __restrict__ rden2,
             float* __restrict__ pself2, int N) {
    int n = (blockIdx.x * blockDim.x + threadIdx.x) >> 4;
    int l = threadIdx.x & 15;
    if (n >= N) return;
    int s0 = eoffs[n], s1 = eoffs[n + 1];
    float adn = ad2[n];
    float vs = as2[n] + adn; vs = (vs >= 0.f) ? vs : NEG_SLOPE * vs;

    float m = vs;
    for (int i = s0 + l; i < s1; i += 16) {
        float v = as2[csr[i]] + adn;
        v = (v >= 0.f) ? v : NEG_SLOPE * v;
        m = fmaxf(m, v);
    }
#pragma unroll
    for (int off = 8; off >= 1; off >>= 1) m = fmaxf(m, __shfl_xor(m, off, 16));
    float d = 0.f;
    for (int i = s0 + l; i < s1; i += 16) {
        float v = as2[csr[i]] + adn;
        v = (v >= 0.f) ? v : NEG_SLOPE * v;
        float p = __expf(v - m);
        d += p;
        pe2[i] = p;
    }
#pragma unroll
    for (int off = 8; off >= 1; off >>= 1) d += __shfl_xor(d, off, 16);
    float ps = __expf(vs - m);
    d += ps;
    if (l == 0) {
        rden2[n] = 1.f / (d + 1e-16f);
        pself2[n] = ps;
    }
}

// ---------------------------------------------------------------------------
// Layer 2 gather + bias + log_softmax. 16 lanes per node (lane = class).
// ---------------------------------------------------------------------------
__global__ __launch_bounds__(256)
void gather2(const int* __restrict__ eoffs, const int* __restrict__ csr,
             const float* __restrict__ pe2, const float* __restrict__ rden2,
             const float* __restrict__ pself2,
             const float* __restrict__ z, const float* __restrict__ b2,
             float* __restrict__ out, int N) {
    int g = threadIdx.x >> 4;
    int l = threadIdx.x & 15;
    int n = blockIdx.x * 16 + g;
    if (n >= N) return;
    int s0 = eoffs[n], s1 = eoffs[n + 1];

    float acc = pself2[n] * z[(long)n * NCLS + l];
    int i = s0;
    for (; i + 4 <= s1; i += 4) {
        int sa = csr[i], sb = csr[i + 1], sc = csr[i + 2], sd = csr[i + 3];
        float pa = pe2[i], pb = pe2[i + 1], pc = pe2[i + 2], pd = pe2[i + 3];
        float za = z[sa * NCLS + l];
        float zb = z[sb * NCLS + l];
        float zc = z[sc * NCLS + l];
        float zd = z[sd * NCLS + l];
        acc = fmaf(za, pa, acc);
        acc = fmaf(zb, pb, acc);
        acc = fmaf(zc, pc, acc);
        acc = fmaf(zd, pd, acc);
    }
    for (; i < s1; ++i) acc = fmaf(z[csr[i] * NCLS + l], pe2[i], acc);

    float o = acc * rden2[n] + b2[l];

    float mx = o;
#pragma unroll
    for (int off = 8; off >= 1; off >>= 1) mx = fmaxf(mx, __shfl_xor(mx, off, 16));
    float ex = __expf(o - mx);
    float sum = ex;
#pragma unroll
    for (int off = 8; off >= 1; off >>= 1) sum += __shfl_xor(sum, off, 16);
    out[(long)n * NCLS + l] = o - mx - __logf(sum);
}

// ---------------------------------------------------------------------------
extern "C" void kernel_launch(void* const* d_in, const int* in_sizes, int n_in,
                              void* d_out, int out_size, void* d_ws, size_t ws_size,
                              hipStream_t stream) {
    const float* x        = (const float*)d_in[0];
    const int*   ei       = (const int*)  d_in[1];
    // d_in[2] = edge_attr (unused by reference)
    const float* W1       = (const float*)d_in[3];
    const float* att_src1 = (const float*)d_in[4];
    const float* att_dst1 = (const float*)d_in[5];
    const float* b1       = (const float*)d_in[6];
    const float* W2       = (const float*)d_in[7];
    const float* att_src2 = (const float*)d_in[8];
    const float* att_dst2 = (const float*)d_in[9];
    const float* b2       = (const float*)d_in[10];
    float* out = (float*)d_out;

    const int N = in_sizes[0] / FIN;        // 50000
    const int E = in_sizes[1] / 2;          // 800000
    const int NB = (N + 255) >> 8;          // 196 buckets
    const int EB = (E + EPB - 1) / EPB;     // 196 edge blocks

    // Workspace layout (bytes), with aliasing for layer-2 temporaries
    char* ws = (char*)d_ws;
    size_t off = 0;
    auto alloc = [&](size_t bytes) { char* p = ws + off; off += (bytes + 255) & ~(size_t)255; return p; };
    int*    bucket_cnt    = (int*)  alloc((size_t)NB * 4);
    int*    bucket_base   = (int*)  alloc((size_t)(NB + 1) * 4);
    int*    bucket_cursor = (int*)  alloc((size_t)NB * 4);
    int2*   tmp           = (int2*) alloc((size_t)E * 8);
    int*    csr           = (int*)  alloc((size_t)E * 4);
    int*    eoffs         = (int*)  alloc((size_t)(N + 1) * 4);
    unsigned short* h1b   = (unsigned short*)alloc((size_t)N * HC1 * 2);  // bf16
    float*  h2            = (float*) alloc((size_t)N * HC1 * 4);
    float*  z             = (float*) alloc((size_t)N * NCLS * 4);
    float2* pe            = (float2*)alloc((size_t)E * 8);     // layer2: pe2 aliases
    float2* rden          = (float2*)alloc((size_t)N * 8);     // layer2: rden2 aliases
    float2* pself         = (float2*)alloc((size_t)N * 8);     // layer2: pself2 aliases
    float*  as1           = (float*) alloc((size_t)N * 2 * 4); // layer2: as2 aliases
    float*  ad1           = (float*) alloc((size_t)N * 2 * 4); // layer2: ad2 aliases
    (void)ws_size;

    float* pe2    = (float*)pe;
    float* rden2  = (float*)rden;
    float* pself2 = (float*)pself;
    float* as2    = as1;
    float* ad2    = ad1;

    hipMemsetAsync(bucket_cnt, 0, (size_t)NB * 4, stream);

    bcnt_kernel<<<EB, 256, 0, stream>>>(ei, bucket_cnt, E, NB);
    bscan_kernel<<<1, 256, 0, stream>>>(bucket_cnt, bucket_base, bucket_cursor, NB);
    binA_kernel<<<EB, 256, 0, stream>>>(ei, bucket_cursor, tmp, E, NB);
    binB_kernel<<<NB, 256, 0, stream>>>(tmp, bucket_base, csr, eoffs, E, N);

    gemm1_mfma<<<(N + 63) / 64, 256, 0, stream>>>(
        x, W1, att_src1, att_dst1, h1b, as1, ad1, N);
    scores1<<<(N + 15) / 16, 256, 0, stream>>>(eoffs, csr, as1, ad1, pe, rden, pself, N);
    gather1<<<(N + 7) / 8, 256, 0, stream>>>(eoffs, csr, pe, rden, pself, h1b, b1, h2, N);

    gemm2_alpha<<<(N + 15) / 16, 256, 0, stream>>>(
        h2, W2, att_src2, att_dst2, z, as2, ad2, N);
    scores2<<<(N + 15) / 16, 256, 0, stream>>>(eoffs, csr, as2, ad2, pe2, rden2, pself2, N);
    gather2<<<(N + 15) / 16, 256, 0, stream>>>(eoffs, csr, pe2, rden2, pself2, z, b2, out, N);
}